// Round 18
// baseline (285.627 us; speedup 1.0000x reference)
//
#include <hip/hip_runtime.h>

// ---------------------------------------------------------------------------
// ONOBlock forward, MI355X (gfx950).  B=4, N=8192, C=256, H=8, D=32.
// fp32 in/out; bf16 MFMA internally (tolerance is 2% of absmax).
// r17 baseline (278.1us) + tail fixes: bilin split-K 16->32 (2x blocks),
// merged transpose_cast launches.  GEMM structure unchanged (converged).
// ---------------------------------------------------------------------------

typedef __attribute__((ext_vector_type(8))) short    bf16x8;   // MFMA A/B frag
typedef __attribute__((ext_vector_type(4))) float    f32x4;    // MFMA C/D frag
typedef __attribute__((ext_vector_type(8))) unsigned short ushortx8;
typedef __attribute__((ext_vector_type(4))) unsigned short ushortx4;

static constexpr int Bn = 4, Nn = 8192, Cn = 256, Hn = 8, Dn = 32;
static constexpr int BN = Bn * Nn;                        // 32768 rows
static constexpr long long S = (long long)BN * Cn;        // 8388608 elems/tensor

#define DEVI __device__ __forceinline__

// async global->LDS, 16B per lane; dest = lds_base + lane*16 (wave-uniform base)
#define GLOAD_LDS16(gsrc, ldst)                                                  \
    __builtin_amdgcn_global_load_lds(                                            \
        (const __attribute__((address_space(1))) unsigned int*)(gsrc),           \
        (__attribute__((address_space(3))) unsigned int*)(ldst), 16, 0, 0)

DEVI unsigned short f2bf(float f) {
    unsigned int u = __builtin_bit_cast(unsigned int, f);
    u += 0x7fffu + ((u >> 16) & 1u);          // RNE
    return (unsigned short)(u >> 16);
}
DEVI float bf2f(unsigned short h) {
    unsigned int u = ((unsigned int)h) << 16;
    return __builtin_bit_cast(float, u);
}

// ---------------------------------------------------------------------------
// Weight transpose + bf16 cast for all 8 weights in one launch.
// ---------------------------------------------------------------------------
__global__ __launch_bounds__(256) void wtrans_all_kernel(
    const float* __restrict__ W0, const float* __restrict__ W1,
    const float* __restrict__ W2, const float* __restrict__ W3,
    const float* __restrict__ W4, const float* __restrict__ W5,
    const float* __restrict__ W6, const float* __restrict__ W7,
    unsigned short* __restrict__ WtAll) {
    __shared__ float tile[256][33];
    const float* W;
    switch (blockIdx.y) {
        case 0: W = W0; break; case 1: W = W1; break;
        case 2: W = W2; break; case 3: W = W3; break;
        case 4: W = W4; break; case 5: W = W5; break;
        case 6: W = W6; break; default: W = W7; break;
    }
    unsigned short* Wt = WtAll + (size_t)blockIdx.y * 65536;
    int t = threadIdx.x;
    int j0 = blockIdx.x * 32;
#pragma unroll
    for (int p = 0; p < 32; ++p) {
        int k = p * 8 + (t >> 5);
        tile[k][t & 31] = W[k * Cn + j0 + (t & 31)];
    }
    __syncthreads();
#pragma unroll
    for (int p = 0; p < 8; ++p) {
        int j = p * 4 + (t >> 6);
        int k0 = (t & 63) * 4;
        ushortx4 o;
        o.x = f2bf(tile[k0 + 0][j]);
        o.y = f2bf(tile[k0 + 1][j]);
        o.z = f2bf(tile[k0 + 2][j]);
        o.w = f2bf(tile[k0 + 3][j]);
        *(ushortx4*)(Wt + (long long)(j0 + j) * Cn + k0) = o;
    }
}

// ---------------------------------------------------------------------------
// PE + LayerNorm for both streams in one launch (grid.y selects stream).
// ---------------------------------------------------------------------------
__global__ __launch_bounds__(256) void peln2_kernel(
    const float* __restrict__ in0, const float* __restrict__ g0, const float* __restrict__ b0,
    unsigned short* __restrict__ o0,
    const float* __restrict__ in1, const float* __restrict__ g1, const float* __restrict__ b1,
    unsigned short* __restrict__ o1) {
    const float* in  = blockIdx.y ? in1 : in0;
    const float* gam = blockIdx.y ? g1 : g0;
    const float* bet = blockIdx.y ? b1 : b0;
    unsigned short* outb = blockIdx.y ? o1 : o0;
    int r = blockIdx.x * 4 + (threadIdx.x >> 6);
    int lane = threadIdx.x & 63;
    int n = r & (Nn - 1);
    int c0 = lane * 4;
    const float* rowp = in + (long long)r * Cn + c0;
    float v0 = rowp[0], v1 = rowp[1], v2 = rowp[2], v3 = rowp[3];
    const float Kf = 0.07195578415606394f;   // ln(10000)/128
    float fn = (float)n;
    float ang0 = fn * expf(-Kf * (float)(2 * lane));
    float ang1 = fn * expf(-Kf * (float)(2 * lane + 1));
    v0 += sinf(ang0); v1 += cosf(ang0);
    v2 += sinf(ang1); v3 += cosf(ang1);
    float s = v0 + v1 + v2 + v3;
#pragma unroll
    for (int m = 1; m < 64; m <<= 1) s += __shfl_xor(s, m, 64);
    float mean = s * (1.0f / 256.0f);
    float d0 = v0 - mean, d1 = v1 - mean, d2 = v2 - mean, d3 = v3 - mean;
    float q = d0 * d0 + d1 * d1 + d2 * d2 + d3 * d3;
#pragma unroll
    for (int m = 1; m < 64; m <<= 1) q += __shfl_xor(q, m, 64);
    float rstd = rsqrtf(q * (1.0f / 256.0f) + 1e-6f);
    float4 g4 = *(const float4*)(gam + c0);
    float4 b4 = *(const float4*)(bet + c0);
    ushortx4 o;
    o.x = f2bf(d0 * rstd * g4.x + b4.x);
    o.y = f2bf(d1 * rstd * g4.y + b4.y);
    o.z = f2bf(d2 * rstd * g4.z + b4.z);
    o.w = f2bf(d3 * rstd * g4.w + b4.w);
    *(ushortx4*)(outb + (long long)r * Cn + c0) = o;
}

// LN only (no PE), fp32 input -> bf16 out (for LN3).
__global__ __launch_bounds__(256) void ln_kernel(const float* __restrict__ in,
                                                 const float* __restrict__ gam,
                                                 const float* __restrict__ bet,
                                                 unsigned short* __restrict__ outb) {
    int r = blockIdx.x * 4 + (threadIdx.x >> 6);
    int lane = threadIdx.x & 63;
    int c0 = lane * 4;
    const float* rowp = in + (long long)r * Cn + c0;
    float v0 = rowp[0], v1 = rowp[1], v2 = rowp[2], v3 = rowp[3];
    float s = v0 + v1 + v2 + v3;
#pragma unroll
    for (int m = 1; m < 64; m <<= 1) s += __shfl_xor(s, m, 64);
    float mean = s * (1.0f / 256.0f);
    float d0 = v0 - mean, d1 = v1 - mean, d2 = v2 - mean, d3 = v3 - mean;
    float q = d0 * d0 + d1 * d1 + d2 * d2 + d3 * d3;
#pragma unroll
    for (int m = 1; m < 64; m <<= 1) q += __shfl_xor(q, m, 64);
    float rstd = rsqrtf(q * (1.0f / 256.0f) + 1e-6f);
    float4 g4 = *(const float4*)(gam + c0);
    float4 b4 = *(const float4*)(bet + c0);
    ushortx4 o;
    o.x = f2bf(d0 * rstd * g4.x + b4.x);
    o.y = f2bf(d1 * rstd * g4.y + b4.y);
    o.z = f2bf(d2 * rstd * g4.z + b4.z);
    o.w = f2bf(d3 * rstd * g4.w + b4.w);
    *(ushortx4*)(outb + (long long)r * Cn + c0) = o;
}

// ---------------------------------------------------------------------------
// Fused QKV GEMM for BOTH streams in one launch.  grid (BN/128, 20).
// ---------------------------------------------------------------------------
__global__ __launch_bounds__(256, 4) void qkv_gemm_kernel(
    const unsigned short* __restrict__ A0, const unsigned short* __restrict__ A1,
    const unsigned short* __restrict__ WtAll,
    const float* __restrict__ bq, const float* __restrict__ bk0,
    const float* __restrict__ bv0, const float* __restrict__ bk1,
    const float* __restrict__ bv1,
    unsigned short* __restrict__ qb, unsigned short* __restrict__ kb0,
    unsigned short* __restrict__ vb0, unsigned short* __restrict__ kb1,
    unsigned short* __restrict__ vb1,
    float* __restrict__ ks0, float* __restrict__ ks1) {
    __shared__ unsigned short As[2][128][64];   // 32 KB, linear (gload_lds dest)
    int t = threadIdx.x;
    int row0 = blockIdx.x * 128;
    int y = blockIdx.y;

    const unsigned short* A;
    const unsigned short* Btw;
    const float* bsel; unsigned short* osel; bool sm; float* ksp;
    int colIn;
    if (y < 12) {
        A = A0; int wid = y >> 2; colIn = (y & 3) * 64;
        Btw = WtAll + (size_t)wid * 65536;
        if (wid == 0)      { bsel = bq;  osel = qb;  sm = true;  ksp = nullptr; }
        else if (wid == 1) { bsel = bk0; osel = kb0; sm = true;  ksp = ks0; }
        else               { bsel = bv0; osel = vb0; sm = false; ksp = nullptr; }
    } else {
        int y2 = y - 12;
        A = A1; int wid = y2 >> 2; colIn = (y2 & 3) * 64;
        Btw = WtAll + (size_t)(3 + wid) * 65536;
        if (wid == 0)      { bsel = bk1; osel = kb1; sm = true;  ksp = ks1; }
        else               { bsel = bv1; osel = vb1; sm = false; ksp = nullptr; }
    }

    int lane = t & 63, w = t >> 6;
    int wr = w >> 1, wc = w & 1;
    int frow = lane & 15, fk = (lane >> 4) * 8;

    bf16x8 bfr[4][2][2];
#pragma unroll
    for (int kt = 0; kt < 4; ++kt)
#pragma unroll
        for (int ks = 0; ks < 2; ++ks)
#pragma unroll
            for (int n = 0; n < 2; ++n)
                bfr[kt][ks][n] = *(const bf16x8*)(
                    Btw + (long long)(colIn + wc * 32 + n * 16 + frow) * Cn
                        + kt * 64 + ks * 32 + fk);

    int srow_in_g = lane >> 3;            // 0..7
    int schunk = lane & 7;                // 16B chunk within 128B row
    auto stageA = [&](int kt, int bf) {
#pragma unroll
        for (int i = 0; i < 4; ++i) {
            int g = w * 4 + i;
            int r = g * 8 + srow_in_g;
            int c = schunk ^ (r & 7);     // pre-swizzled source chunk
            const unsigned short* src = A + (long long)(row0 + r) * Cn + kt * 64 + c * 8;
            GLOAD_LDS16(src, &As[bf][g * 8][0]);
        }
    };

    f32x4 acc[4][2];
#pragma unroll
    for (int m = 0; m < 4; ++m)
#pragma unroll
        for (int n = 0; n < 2; ++n) {
            acc[m][n][0] = 0.f; acc[m][n][1] = 0.f;
            acc[m][n][2] = 0.f; acc[m][n][3] = 0.f;
        }

    stageA(0, 0);
    int bf = 0;
#pragma unroll
    for (int kt = 0; kt < 4; ++kt) {
        if (kt < 3) {
            stageA(kt + 1, bf ^ 1);
            asm volatile("s_waitcnt vmcnt(4)" ::: "memory");   // my stageA(kt) landed
        } else {
            asm volatile("s_waitcnt vmcnt(0)" ::: "memory");
        }
        __builtin_amdgcn_s_barrier();
#pragma unroll
        for (int ks = 0; ks < 2; ++ks) {
#pragma unroll
            for (int m = 0; m < 4; ++m) {
                int arow = wr * 64 + m * 16 + frow;
                bf16x8 afr = *(const bf16x8*)&As[bf][arow][(ks * 32 + fk) ^ ((arow & 7) << 3)];
#pragma unroll
                for (int n = 0; n < 2; ++n)
                    acc[m][n] = __builtin_amdgcn_mfma_f32_16x16x32_bf16(afr, bfr[kt][ks][n],
                                                                        acc[m][n], 0, 0, 0);
            }
        }
        __builtin_amdgcn_s_barrier();
        bf ^= 1;
    }

    if (sm) {
        int colA = colIn + wc * 32 + frow;
        float b0 = bsel[colA], b1 = bsel[colA + 16];
        float ps0 = 0.f, ps1 = 0.f;
#pragma unroll
        for (int m = 0; m < 4; ++m) {
            int rbase = row0 + wr * 64 + m * 16 + (lane >> 4) * 4;
#pragma unroll
            for (int r = 0; r < 4; ++r) {
                float e0 = __expf(acc[m][0][r] + b0);
                float e1 = __expf(acc[m][1][r] + b1);
                float ssum = e0 + e1;
#pragma unroll
                for (int msk = 1; msk < 16; msk <<= 1) ssum += __shfl_xor(ssum, msk);
                float inv = 1.0f / ssum;
                e0 *= inv; e1 *= inv;
                long long idx = (long long)(rbase + r) * Cn + colA;
                osel[idx] = f2bf(e0);
                osel[idx + 16] = f2bf(e1);
                ps0 += e0; ps1 += e1;
            }
        }
        if (ksp) {
            ps0 += __shfl_xor(ps0, 16); ps0 += __shfl_xor(ps0, 32);
            ps1 += __shfl_xor(ps1, 16); ps1 += __shfl_xor(ps1, 32);
            if (lane < 16) {
                int b = row0 >> 13;
                atomicAdd(ksp + (b * 8 + (colA >> 5)) * 32 + (colA & 31), ps0);
                int c2 = colA + 16;
                atomicAdd(ksp + (b * 8 + (c2 >> 5)) * 32 + (c2 & 31), ps1);
            }
        }
    } else {
#pragma unroll
        for (int m = 0; m < 4; ++m) {
            int rbase = row0 + wr * 64 + m * 16 + (lane >> 4) * 4;
#pragma unroll
            for (int n = 0; n < 2; ++n) {
                int col = colIn + wc * 32 + n * 16 + frow;
                float bv = bsel[col];
#pragma unroll
                for (int r = 0; r < 4; ++r) {
                    long long idx = (long long)(rbase + r) * Cn + col;
                    osel[idx] = f2bf(acc[m][n][r] + bv);
                }
            }
        }
    }
}

// ---------------------------------------------------------------------------
// Tail GEMM.  EPI: 0 plain->bf16, 1 GELU(sigmoid)->bf16, 2 +resid->fp32,
// 3 +resid->fp32 & bf16(x*softplus(mu)), 4 LeakyReLU->fp32 per-batch Bt.
// ---------------------------------------------------------------------------
template <int EPI>
__global__ __launch_bounds__(256, 4) void gemm_kernel(
    const unsigned short* __restrict__ A, const unsigned short* __restrict__ Bt,
    const float* __restrict__ bias, float* __restrict__ outF,
    const float* __restrict__ resid, unsigned short* __restrict__ outB,
    unsigned short* __restrict__ outB2, const float* __restrict__ mu) {
    __shared__ unsigned short As[2][128][64];   // 32 KB, linear (gload_lds dest)
    int t = threadIdx.x;
    int row0 = blockIdx.x * 128;
    int col0 = blockIdx.y * 64;
    if (EPI == 4) Bt += (size_t)(row0 >> 13) * Cn * Cn;   // per-batch B
    int lane = t & 63, w = t >> 6;
    int wr = w >> 1, wc = w & 1;
    int frow = lane & 15, fk = (lane >> 4) * 8;

    bf16x8 bfr[4][2][2];
#pragma unroll
    for (int kt = 0; kt < 4; ++kt)
#pragma unroll
        for (int ks = 0; ks < 2; ++ks)
#pragma unroll
            for (int n = 0; n < 2; ++n)
                bfr[kt][ks][n] = *(const bf16x8*)(
                    Bt + (long long)(col0 + wc * 32 + n * 16 + frow) * Cn
                       + kt * 64 + ks * 32 + fk);

    int srow_in_g = lane >> 3;
    int schunk = lane & 7;
    auto stageA = [&](int kt, int bf) {
#pragma unroll
        for (int i = 0; i < 4; ++i) {
            int g = w * 4 + i;
            int r = g * 8 + srow_in_g;
            int c = schunk ^ (r & 7);
            const unsigned short* src = A + (long long)(row0 + r) * Cn + kt * 64 + c * 8;
            GLOAD_LDS16(src, &As[bf][g * 8][0]);
        }
    };

    f32x4 acc[4][2];
#pragma unroll
    for (int m = 0; m < 4; ++m)
#pragma unroll
        for (int n = 0; n < 2; ++n) {
            acc[m][n][0] = 0.f; acc[m][n][1] = 0.f;
            acc[m][n][2] = 0.f; acc[m][n][3] = 0.f;
        }

    stageA(0, 0);
    int bf = 0;
#pragma unroll
    for (int kt = 0; kt < 4; ++kt) {
        if (kt < 3) {
            stageA(kt + 1, bf ^ 1);
            asm volatile("s_waitcnt vmcnt(4)" ::: "memory");
        } else {
            asm volatile("s_waitcnt vmcnt(0)" ::: "memory");
        }
        __builtin_amdgcn_s_barrier();
#pragma unroll
        for (int ks = 0; ks < 2; ++ks) {
#pragma unroll
            for (int m = 0; m < 4; ++m) {
                int arow = wr * 64 + m * 16 + frow;
                bf16x8 afr = *(const bf16x8*)&As[bf][arow][(ks * 32 + fk) ^ ((arow & 7) << 3)];
#pragma unroll
                for (int n = 0; n < 2; ++n)
                    acc[m][n] = __builtin_amdgcn_mfma_f32_16x16x32_bf16(afr, bfr[kt][ks][n],
                                                                        acc[m][n], 0, 0, 0);
            }
        }
        __builtin_amdgcn_s_barrier();
        bf ^= 1;
    }

    float spv[2];
    if (EPI == 3) {
#pragma unroll
        for (int n = 0; n < 2; ++n) {
            float m_ = mu[col0 + wc * 32 + n * 16 + frow];
            spv[n] = (m_ > 20.f) ? m_ : log1pf(expf(m_));
        }
    }
#pragma unroll
    for (int m = 0; m < 4; ++m) {
        int rbase = row0 + wr * 64 + m * 16 + (lane >> 4) * 4;
#pragma unroll
        for (int n = 0; n < 2; ++n) {
            int col = col0 + wc * 32 + n * 16 + frow;
            float bv = (EPI == 4) ? 0.0f : bias[col];
#pragma unroll
            for (int r = 0; r < 4; ++r) {
                long long idx = (long long)(rbase + r) * Cn + col;
                float v = acc[m][n][r] + bv;
                if (EPI == 0) {
                    outB[idx] = f2bf(v);
                } else if (EPI == 1) {
                    float sg = 1.0f / (1.0f + __expf(-1.702f * v));
                    outB[idx] = f2bf(v * sg);
                } else if (EPI == 2) {
                    outF[idx] = v + resid[idx];
                } else if (EPI == 3) {
                    float xv = v + resid[idx];
                    outF[idx] = xv;
                    outB2[idx] = f2bf(xv * spv[n]);
                } else {
                    outF[idx] = (v >= 0.0f) ? v : 0.01f * v;
                }
            }
        }
    }
}

// ---------------------------------------------------------------------------
// kv_gemm (MFMA) for BOTH streams: grid (32, 32, 2); z selects stream.
// ---------------------------------------------------------------------------
__global__ __launch_bounds__(256) void kv_gemm_kernel(
    const unsigned short* __restrict__ kbs0, const unsigned short* __restrict__ vbs0,
    float* __restrict__ kv0p,
    const unsigned short* __restrict__ kbs1, const unsigned short* __restrict__ vbs1,
    float* __restrict__ kv1p) {
    const unsigned short* kb = blockIdx.z ? kbs1 : kbs0;
    const unsigned short* vb = blockIdx.z ? vbs1 : vbs0;
    float* kv = blockIdx.z ? kv1p : kv0p;
    __shared__ unsigned short kl[256][36];
    __shared__ unsigned short vl[256][36];
    __shared__ float red[4][1024];
    int bh = blockIdx.x, b = bh >> 3, h = bh & 7;
    int n0 = blockIdx.y * 256;
    int t = threadIdx.x, lane = t & 63, w = t >> 6;
    {
        int r0 = t >> 2, ch = (t & 3) * 8;
        long long gbase = ((long long)(b * Nn + n0)) * Cn + h * Dn + ch;
#pragma unroll
        for (int i = 0; i < 4; ++i) {
            int r = r0 + i * 64;
            ushortx8 dk = *(const ushortx8*)(kb + gbase + (long long)r * Cn);
            ushortx8 dv = *(const ushortx8*)(vb + gbase + (long long)r * Cn);
            ushortx4 k0 = {dk[0], dk[1], dk[2], dk[3]};
            ushortx4 k1 = {dk[4], dk[5], dk[6], dk[7]};
            ushortx4 v0 = {dv[0], dv[1], dv[2], dv[3]};
            ushortx4 v1 = {dv[4], dv[5], dv[6], dv[7]};
            *(ushortx4*)&kl[r][ch]     = k0;
            *(ushortx4*)&kl[r][ch + 4] = k1;
            *(ushortx4*)&vl[r][ch]     = v0;
            *(ushortx4*)&vl[r][ch + 4] = v1;
        }
    }
    __syncthreads();
    int frow = lane & 15, fk = (lane >> 4) * 8;
    f32x4 acc[2][2];
#pragma unroll
    for (int m = 0; m < 2; ++m)
#pragma unroll
        for (int n = 0; n < 2; ++n) {
            acc[m][n][0] = 0.f; acc[m][n][1] = 0.f;
            acc[m][n][2] = 0.f; acc[m][n][3] = 0.f;
        }
    int nb = w * 64;
#pragma unroll
    for (int s = 0; s < 2; ++s) {
        int kk = nb + s * 32 + fk;
        bf16x8 a0, a1, b0, b1;
#pragma unroll
        for (int j = 0; j < 8; ++j) {
            a0[j] = (short)kl[kk + j][frow];
            a1[j] = (short)kl[kk + j][16 + frow];
            b0[j] = (short)vl[kk + j][frow];
            b1[j] = (short)vl[kk + j][16 + frow];
        }
        acc[0][0] = __builtin_amdgcn_mfma_f32_16x16x32_bf16(a0, b0, acc[0][0], 0, 0, 0);
        acc[0][1] = __builtin_amdgcn_mfma_f32_16x16x32_bf16(a0, b1, acc[0][1], 0, 0, 0);
        acc[1][0] = __builtin_amdgcn_mfma_f32_16x16x32_bf16(a1, b0, acc[1][0], 0, 0, 0);
        acc[1][1] = __builtin_amdgcn_mfma_f32_16x16x32_bf16(a1, b1, acc[1][1], 0, 0, 0);
    }
#pragma unroll
    for (int m = 0; m < 2; ++m)
#pragma unroll
        for (int n = 0; n < 2; ++n)
#pragma unroll
            for (int r = 0; r < 4; ++r)
                red[w][(m * 16 + (lane >> 4) * 4 + r) * 32 + n * 16 + frow] = acc[m][n][r];
    __syncthreads();
    float* out = kv + (long long)bh * 1024;
#pragma unroll
    for (int i = 0; i < 4; ++i) {
        int idx = t + i * 256;
        atomicAdd(out + idx, red[0][idx] + red[1][idx] + red[2][idx] + red[3][idx]);
    }
}

// ---------------------------------------------------------------------------
// attn epilogue (MFMA): out[128,32] = q + (q@KV0)*dinv0 + (q@KV1)*dinv1.
// ---------------------------------------------------------------------------
__global__ __launch_bounds__(256) void attn_out_kernel(
    const unsigned short* __restrict__ qb, const float* __restrict__ kv0,
    const float* __restrict__ ks0, const float* __restrict__ kv1,
    const float* __restrict__ ks1, unsigned short* __restrict__ outb) {
    __shared__ unsigned short BT[80][40];   // [col][k], padded stride 80B
    int bh = blockIdx.y;
    int b = bh >> 3, h = bh & 7;
    int n0 = blockIdx.x * 128;
    int t = threadIdx.x;
    {
        int e = t & 31, d0 = t >> 5;
        const float* KV0 = kv0 + (long long)bh * 1024;
        const float* KV1 = kv1 + (long long)bh * 1024;
#pragma unroll
        for (int i = 0; i < 4; ++i) {
            int d = d0 + 8 * i;
            BT[e][d]      = f2bf(KV0[d * 32 + e]);
            BT[32 + e][d] = f2bf(KV1[d * 32 + e]);
        }
        if (t < 32)            BT[64][t]      = f2bf(ks0[bh * 32 + t]);
        else if (t < 64)       BT[65][t - 32] = f2bf(ks1[bh * 32 + (t - 32)]);
        if (t < 224) {
            int c = 66 + (t >> 4), k2 = (t & 15) * 2;
            BT[c][k2] = 0; BT[c][k2 + 1] = 0;
        }
    }
    __syncthreads();

    int lane = t & 63, w = t >> 6;
    int frow = lane & 15, fk = (lane >> 4) * 8;
    bf16x8 bfr[5];
#pragma unroll
    for (int n = 0; n < 5; ++n)
        bfr[n] = *(const bf16x8*)&BT[n * 16 + frow][fk];

    f32x4 acc[2][5];
#pragma unroll
    for (int m = 0; m < 2; ++m)
#pragma unroll
        for (int n = 0; n < 5; ++n) {
            acc[m][n][0] = 0.f; acc[m][n][1] = 0.f;
            acc[m][n][2] = 0.f; acc[m][n][3] = 0.f;
        }
    long long grow0 = (long long)b * Nn + n0 + w * 32;
#pragma unroll
    for (int m = 0; m < 2; ++m) {
        bf16x8 afr = *(const bf16x8*)(qb + (grow0 + m * 16 + frow) * Cn + h * Dn + fk);
#pragma unroll
        for (int n = 0; n < 5; ++n)
            acc[m][n] = __builtin_amdgcn_mfma_f32_16x16x32_bf16(afr, bfr[n],
                                                                acc[m][n], 0, 0, 0);
    }
#pragma unroll
    for (int m = 0; m < 2; ++m) {
#pragma unroll
        for (int r = 0; r < 4; ++r) {
            float s0 = __shfl(acc[m][4][r], lane & 48, 64);
            float s1 = __shfl(acc[m][4][r], (lane & 48) + 1, 64);
            float inv0 = 1.0f / s0, inv1 = 1.0f / s1;
            long long row = grow0 + m * 16 + (lane >> 4) * 4 + r;
            long long base = row * Cn + h * Dn + (lane & 15);
            float q0 = bf2f(qb[base]), q1 = bf2f(qb[base + 16]);
            outb[base]      = f2bf(q0 + acc[m][0][r] * inv0 + acc[m][2][r] * inv1);
            outb[base + 16] = f2bf(q1 + acc[m][1][r] * inv0 + acc[m][3][r] * inv1);
        }
    }
}

// ---------------------------------------------------------------------------
// Batched transpose + bf16 cast for BOTH sources in one launch:
// z < Bn: out0[b][c][n] = bf16(in0[b][n][c]);  z >= Bn: out1 from in1.
// grid (Nn/64, Cn/32, 2*Bn).
// ---------------------------------------------------------------------------
__global__ __launch_bounds__(256) void transpose_cast2_kernel(
    const float* __restrict__ in0, unsigned short* __restrict__ out0,
    const float* __restrict__ in1, unsigned short* __restrict__ out1) {
    __shared__ float tile[64][33];
    int z = blockIdx.z;
    const float* in = (z < Bn) ? in0 : in1;
    unsigned short* out = (z < Bn) ? out0 : out1;
    int b = (z < Bn) ? z : z - Bn;
    int n0 = blockIdx.x * 64;
    int c0 = blockIdx.y * 32;
    int t = threadIdx.x;
    int r = t >> 2;
    int cc = (t & 3) * 8;
    const float* src = in + ((long long)b * Nn + n0 + r) * Cn + c0 + cc;
    float4 a0 = *(const float4*)src;
    float4 a1 = *(const float4*)(src + 4);
    tile[r][cc + 0] = a0.x; tile[r][cc + 1] = a0.y;
    tile[r][cc + 2] = a0.z; tile[r][cc + 3] = a0.w;
    tile[r][cc + 4] = a1.x; tile[r][cc + 5] = a1.y;
    tile[r][cc + 6] = a1.z; tile[r][cc + 7] = a1.w;
    __syncthreads();
    int c = t >> 3;
    int nn = (t & 7) * 8;
    ushortx8 o;
#pragma unroll
    for (int j = 0; j < 8; ++j) o[j] = f2bf(tile[nn + j][c]);
    *(ushortx8*)(out + ((long long)b * Cn + c0 + c) * Nn + n0 + nn) = o;
}

// ---------------------------------------------------------------------------
// Split-K bilinear GEMM: xtfxT[b][f][c] += sum_{k-range} fxT[b][f][k]*xT[b][c][k]
// 32 splits of K=256.  grid (2, 4, 128) = 1024 blocks (4/CU).
// ---------------------------------------------------------------------------
__global__ __launch_bounds__(256, 2) void bilin_gemm_kernel(
    const unsigned short* __restrict__ A, const unsigned short* __restrict__ Bm,
    float* __restrict__ Cacc) {
    __shared__ unsigned short As[128][72];
    __shared__ unsigned short Bs[64][72];
    int t = threadIdx.x;
    int b = blockIdx.z >> 5;
    int split = blockIdx.z & 31;
    int row0 = blockIdx.x * 128;   // f
    int col0 = blockIdx.y * 64;    // c
    const unsigned short* Ab = A + (long long)b * Cn * Nn;
    const unsigned short* Bb = Bm + (long long)b * Cn * Nn;
    int lane = t & 63, w = t >> 6;
    int wr = w >> 1, wc = w & 1;
    int frow = lane & 15, fk = (lane >> 4) * 8;
    f32x4 acc[4][2];
#pragma unroll
    for (int m = 0; m < 4; ++m)
#pragma unroll
        for (int n = 0; n < 2; ++n) {
            acc[m][n][0] = 0.f; acc[m][n][1] = 0.f;
            acc[m][n][2] = 0.f; acc[m][n][3] = 0.f;
        }
    int sr = t >> 3, sc = (t & 7) * 8;
    for (int kt = 0; kt < 4; ++kt) {
        int k0 = split * 256 + kt * 64;
#pragma unroll
        for (int p = 0; p < 4; ++p) {
            int rr = sr + p * 32;
            ushortx8 d = *(const ushortx8*)(Ab + (long long)(row0 + rr) * Nn + k0 + sc);
            *(ushortx8*)&As[rr][sc] = d;
        }
#pragma unroll
        for (int p = 0; p < 2; ++p) {
            int br = sr + p * 32;
            ushortx8 d = *(const ushortx8*)(Bb + (long long)(col0 + br) * Nn + k0 + sc);
            *(ushortx8*)&Bs[br][sc] = d;
        }
        __syncthreads();
#pragma unroll
        for (int ks = 0; ks < 2; ++ks) {
            bf16x8 bfr[2];
#pragma unroll
            for (int n = 0; n < 2; ++n)
                bfr[n] = *(const bf16x8*)&Bs[wc * 32 + n * 16 + frow][ks * 32 + fk];
#pragma unroll
            for (int m = 0; m < 4; ++m) {
                bf16x8 afr = *(const bf16x8*)&As[wr * 64 + m * 16 + frow][ks * 32 + fk];
#pragma unroll
                for (int n = 0; n < 2; ++n)
                    acc[m][n] = __builtin_amdgcn_mfma_f32_16x16x32_bf16(afr, bfr[n],
                                                                        acc[m][n], 0, 0, 0);
            }
        }
        __syncthreads();
    }
    float* base = Cacc + (long long)b * Cn * Cn;
#pragma unroll
    for (int m = 0; m < 4; ++m) {
        int rbase = row0 + wr * 64 + m * 16 + (lane >> 4) * 4;
#pragma unroll
        for (int n = 0; n < 2; ++n) {
            int col = col0 + wc * 32 + n * 16 + frow;
#pragma unroll
            for (int r = 0; r < 4; ++r)
                atomicAdd(base + (long long)(rbase + r) * Cn + col, acc[m][n][r]);
        }
    }
}

// fp32 -> bf16 cast, 4 elems/thread.
__global__ __launch_bounds__(256) void castf2b_kernel(const float* __restrict__ in,
                                                      unsigned short* __restrict__ out) {
    int i = (blockIdx.x * 256 + threadIdx.x) * 4;
    float4 v = *(const float4*)(in + i);
    ushortx4 o;
    o.x = f2bf(v.x); o.y = f2bf(v.y); o.z = f2bf(v.z); o.w = f2bf(v.w);
    *(ushortx4*)(out + i) = o;
}

// ---------------------------------------------------------------------------
extern "C" void kernel_launch(void* const* d_in, const int* in_sizes, int n_in,
                              void* d_out, int out_size, void* d_ws, size_t ws_size,
                              hipStream_t stream) {
    const float* input  = (const float*)d_in[0];
    const float* fx     = (const float*)d_in[1];
    const float* inputf = (const float*)d_in[2];
    const float* ln1g = (const float*)d_in[3],  *ln1b = (const float*)d_in[4];
    const float* ln2g = (const float*)d_in[5],  *ln2b = (const float*)d_in[6];
    const float* ln3g = (const float*)d_in[7],  *ln3b = (const float*)d_in[8];
    const float* Wq  = (const float*)d_in[9],   *bq  = (const float*)d_in[10];
    const float* Wk0 = (const float*)d_in[11],  *bk0 = (const float*)d_in[12];
    const float* Wv0 = (const float*)d_in[13],  *bv0 = (const float*)d_in[14];
    const float* Wk1 = (const float*)d_in[15],  *bk1 = (const float*)d_in[16];
    const float* Wv1 = (const float*)d_in[17],  *bv1 = (const float*)d_in[18];
    const float* Wo  = (const float*)d_in[19],  *bo  = (const float*)d_in[20];
    const float* Wm1 = (const float*)d_in[21],  *bm1 = (const float*)d_in[22];
    const float* Wm2 = (const float*)d_in[23],  *bm2 = (const float*)d_in[24];
    const float* mu  = (const float*)d_in[25];

    float* xOut  = (float*)d_out;        // output 0: x
    float* fxOut = xOut + S;             // output 1: fx_new

    char* ws = (char*)d_ws;
    const size_t SB = (size_t)S * 2;     // 16 MB bf16 buffer
    unsigned short* x1b  = (unsigned short*)(ws + 0 * SB);
    unsigned short* f1b  = (unsigned short*)(ws + 1 * SB);
    unsigned short* qb   = (unsigned short*)(ws + 2 * SB);
    unsigned short* kb   = (unsigned short*)(ws + 3 * SB);
    unsigned short* vb   = (unsigned short*)(ws + 4 * SB);
    unsigned short* outb = (unsigned short*)(ws + 5 * SB);
    unsigned short* kb2  = (unsigned short*)(ws + 6 * SB);
    unsigned short* vb2  = (unsigned short*)(ws + 7 * SB);
    unsigned short* Wt   = (unsigned short*)(ws + 8 * SB);               // 8 x 64K bf16
    unsigned short* xtT  = (unsigned short*)(ws + 8 * SB + (size_t)8 * 65536 * 2);
    float* zbase = (float*)(ws + 8 * SB + (size_t)8 * 65536 * 2 + (size_t)Bn * 65536 * 2);
    float* kv0   = zbase;                 // 32768
    float* kv1   = zbase + 32768;         // 32768
    float* ks0   = zbase + 65536;         // 1024
    float* ks1   = zbase + 66560;         // 1024
    float* xtfxT = zbase + 67584;         // 262144  [b][f][c]
    const size_t ZFLOATS = 67584 + 262144;

    hipMemsetAsync(zbase, 0, ZFLOATS * sizeof(float), stream);

    wtrans_all_kernel<<<dim3(8, 8), 256, 0, stream>>>(Wq, Wk0, Wv0, Wk1, Wv1, Wo, Wm1, Wm2, Wt);

    peln2_kernel<<<dim3(BN / 4, 2), 256, 0, stream>>>(input, ln1g, ln1b, x1b,
                                                      inputf, ln2g, ln2b, f1b);

    // ALL 5 QKV GEMMs in one dispatch (both streams)
    qkv_gemm_kernel<<<dim3(BN / 128, 20), 256, 0, stream>>>(
        f1b, x1b, Wt, bq, bk0, bv0, bk1, bv1,
        qb, kb, vb, kb2, vb2, ks0, ks1);
    // both kv reductions in one dispatch
    kv_gemm_kernel<<<dim3(32, 32, 2), 256, 0, stream>>>(kb, vb, kv0, kb2, vb2, kv1);

    attn_out_kernel<<<dim3(Nn / 128, Bn * Hn), 256, 0, stream>>>(qb, kv0, ks0, kv1, ks1, outb);

    dim3 ggrid(BN / 128, 4);
    // x = out @ Wo + bo + input   -> d_out[0] (fp32)
    gemm_kernel<2><<<ggrid, 256, 0, stream>>>(outb, Wt + (size_t)5 * 65536, bo,
                                              xOut, input, nullptr, nullptr, nullptr);
    // MLP
    ln_kernel<<<BN / 4, 256, 0, stream>>>(xOut, ln3g, ln3b, f1b);
    gemm_kernel<1><<<ggrid, 256, 0, stream>>>(f1b, Wt + (size_t)6 * 65536, bm1,
                                              nullptr, nullptr, x1b, nullptr, nullptr);
    gemm_kernel<3><<<ggrid, 256, 0, stream>>>(x1b, Wt + (size_t)7 * 65536, bm2,
                                              xOut, xOut, nullptr, qb, mu);

    // bilinear fx update: both transposes in one launch
    transpose_cast2_kernel<<<dim3(Nn / 64, Cn / 32, 2 * Bn), 256, 0, stream>>>(
        xOut, kb, fx, vb);
    bilin_gemm_kernel<<<dim3(2, 4, 128), 256, 0, stream>>>(vb, kb, xtfxT);
    castf2b_kernel<<<(int)(Bn * 65536 / 1024), 256, 0, stream>>>(xtfxT, xtT);
    gemm_kernel<4><<<ggrid, 256, 0, stream>>>(qb, xtT, nullptr,
                                              fxOut, nullptr, nullptr, nullptr, nullptr);
}

// Round 19
// 270.926 us; speedup vs baseline: 1.0543x; 1.0543x over previous
//
#include <hip/hip_runtime.h>

// ---------------------------------------------------------------------------
// ONOBlock forward, MI355X (gfx950).  B=4, N=8192, C=256, H=8, D=32.
// fp32 in/out; bf16 MFMA internally (tolerance is 2% of absmax).
// r17 baseline (278.1us) + qkv tile widened to 128x128 (grid.y 20->10):
// halves A staging per output, doubles MFMA per barrier.  B frags per-kt.
// Tails/bilin/transpose exactly r17.
// ---------------------------------------------------------------------------

typedef __attribute__((ext_vector_type(8))) short    bf16x8;   // MFMA A/B frag
typedef __attribute__((ext_vector_type(4))) float    f32x4;    // MFMA C/D frag
typedef __attribute__((ext_vector_type(8))) unsigned short ushortx8;
typedef __attribute__((ext_vector_type(4))) unsigned short ushortx4;

static constexpr int Bn = 4, Nn = 8192, Cn = 256, Hn = 8, Dn = 32;
static constexpr int BN = Bn * Nn;                        // 32768 rows
static constexpr long long S = (long long)BN * Cn;        // 8388608 elems/tensor

#define DEVI __device__ __forceinline__

// async global->LDS, 16B per lane; dest = lds_base + lane*16 (wave-uniform base)
#define GLOAD_LDS16(gsrc, ldst)                                                  \
    __builtin_amdgcn_global_load_lds(                                            \
        (const __attribute__((address_space(1))) unsigned int*)(gsrc),           \
        (__attribute__((address_space(3))) unsigned int*)(ldst), 16, 0, 0)

DEVI unsigned short f2bf(float f) {
    unsigned int u = __builtin_bit_cast(unsigned int, f);
    u += 0x7fffu + ((u >> 16) & 1u);          // RNE
    return (unsigned short)(u >> 16);
}
DEVI float bf2f(unsigned short h) {
    unsigned int u = ((unsigned int)h) << 16;
    return __builtin_bit_cast(float, u);
}

// ---------------------------------------------------------------------------
// Weight transpose + bf16 cast for all 8 weights in one launch.
// ---------------------------------------------------------------------------
__global__ __launch_bounds__(256) void wtrans_all_kernel(
    const float* __restrict__ W0, const float* __restrict__ W1,
    const float* __restrict__ W2, const float* __restrict__ W3,
    const float* __restrict__ W4, const float* __restrict__ W5,
    const float* __restrict__ W6, const float* __restrict__ W7,
    unsigned short* __restrict__ WtAll) {
    __shared__ float tile[256][33];
    const float* W;
    switch (blockIdx.y) {
        case 0: W = W0; break; case 1: W = W1; break;
        case 2: W = W2; break; case 3: W = W3; break;
        case 4: W = W4; break; case 5: W = W5; break;
        case 6: W = W6; break; default: W = W7; break;
    }
    unsigned short* Wt = WtAll + (size_t)blockIdx.y * 65536;
    int t = threadIdx.x;
    int j0 = blockIdx.x * 32;
#pragma unroll
    for (int p = 0; p < 32; ++p) {
        int k = p * 8 + (t >> 5);
        tile[k][t & 31] = W[k * Cn + j0 + (t & 31)];
    }
    __syncthreads();
#pragma unroll
    for (int p = 0; p < 8; ++p) {
        int j = p * 4 + (t >> 6);
        int k0 = (t & 63) * 4;
        ushortx4 o;
        o.x = f2bf(tile[k0 + 0][j]);
        o.y = f2bf(tile[k0 + 1][j]);
        o.z = f2bf(tile[k0 + 2][j]);
        o.w = f2bf(tile[k0 + 3][j]);
        *(ushortx4*)(Wt + (long long)(j0 + j) * Cn + k0) = o;
    }
}

// ---------------------------------------------------------------------------
// PE + LayerNorm for both streams in one launch (grid.y selects stream).
// ---------------------------------------------------------------------------
__global__ __launch_bounds__(256) void peln2_kernel(
    const float* __restrict__ in0, const float* __restrict__ g0, const float* __restrict__ b0,
    unsigned short* __restrict__ o0,
    const float* __restrict__ in1, const float* __restrict__ g1, const float* __restrict__ b1,
    unsigned short* __restrict__ o1) {
    const float* in  = blockIdx.y ? in1 : in0;
    const float* gam = blockIdx.y ? g1 : g0;
    const float* bet = blockIdx.y ? b1 : b0;
    unsigned short* outb = blockIdx.y ? o1 : o0;
    int r = blockIdx.x * 4 + (threadIdx.x >> 6);
    int lane = threadIdx.x & 63;
    int n = r & (Nn - 1);
    int c0 = lane * 4;
    const float* rowp = in + (long long)r * Cn + c0;
    float v0 = rowp[0], v1 = rowp[1], v2 = rowp[2], v3 = rowp[3];
    const float Kf = 0.07195578415606394f;   // ln(10000)/128
    float fn = (float)n;
    float ang0 = fn * expf(-Kf * (float)(2 * lane));
    float ang1 = fn * expf(-Kf * (float)(2 * lane + 1));
    v0 += sinf(ang0); v1 += cosf(ang0);
    v2 += sinf(ang1); v3 += cosf(ang1);
    float s = v0 + v1 + v2 + v3;
#pragma unroll
    for (int m = 1; m < 64; m <<= 1) s += __shfl_xor(s, m, 64);
    float mean = s * (1.0f / 256.0f);
    float d0 = v0 - mean, d1 = v1 - mean, d2 = v2 - mean, d3 = v3 - mean;
    float q = d0 * d0 + d1 * d1 + d2 * d2 + d3 * d3;
#pragma unroll
    for (int m = 1; m < 64; m <<= 1) q += __shfl_xor(q, m, 64);
    float rstd = rsqrtf(q * (1.0f / 256.0f) + 1e-6f);
    float4 g4 = *(const float4*)(gam + c0);
    float4 b4 = *(const float4*)(bet + c0);
    ushortx4 o;
    o.x = f2bf(d0 * rstd * g4.x + b4.x);
    o.y = f2bf(d1 * rstd * g4.y + b4.y);
    o.z = f2bf(d2 * rstd * g4.z + b4.z);
    o.w = f2bf(d3 * rstd * g4.w + b4.w);
    *(ushortx4*)(outb + (long long)r * Cn + c0) = o;
}

// LN only (no PE), fp32 input -> bf16 out (for LN3).
__global__ __launch_bounds__(256) void ln_kernel(const float* __restrict__ in,
                                                 const float* __restrict__ gam,
                                                 const float* __restrict__ bet,
                                                 unsigned short* __restrict__ outb) {
    int r = blockIdx.x * 4 + (threadIdx.x >> 6);
    int lane = threadIdx.x & 63;
    int c0 = lane * 4;
    const float* rowp = in + (long long)r * Cn + c0;
    float v0 = rowp[0], v1 = rowp[1], v2 = rowp[2], v3 = rowp[3];
    float s = v0 + v1 + v2 + v3;
#pragma unroll
    for (int m = 1; m < 64; m <<= 1) s += __shfl_xor(s, m, 64);
    float mean = s * (1.0f / 256.0f);
    float d0 = v0 - mean, d1 = v1 - mean, d2 = v2 - mean, d3 = v3 - mean;
    float q = d0 * d0 + d1 * d1 + d2 * d2 + d3 * d3;
#pragma unroll
    for (int m = 1; m < 64; m <<= 1) q += __shfl_xor(q, m, 64);
    float rstd = rsqrtf(q * (1.0f / 256.0f) + 1e-6f);
    float4 g4 = *(const float4*)(gam + c0);
    float4 b4 = *(const float4*)(bet + c0);
    ushortx4 o;
    o.x = f2bf(d0 * rstd * g4.x + b4.x);
    o.y = f2bf(d1 * rstd * g4.y + b4.y);
    o.z = f2bf(d2 * rstd * g4.z + b4.z);
    o.w = f2bf(d3 * rstd * g4.w + b4.w);
    *(ushortx4*)(outb + (long long)r * Cn + c0) = o;
}

// ---------------------------------------------------------------------------
// Fused QKV GEMM, 128x128 tiles, BOTH streams.  grid (BN/128, 10):
//   y in [0,6): f-stream: wid=y>>1 (0=q sm | 1=k0 sm+ks0 | 2=v0), col=(y&1)*128
//   y in [6,10): x-stream: wid=(y-6)>>1 (0=k1 sm+ks1 | 1=v1)
// Wave (2x2): 64 rows x 64 cols (4 n-frags).  B frags loaded per-kt (L2-hot).
// vmcnt(4) safety: stage(kt) is >=12 ops older than all VMEM issued this
// iteration (8 B + 4 stage(kt+1)), so <=4-outstanding => stage(kt) retired;
// compiler inserts its own waits for B-frag uses.
// ---------------------------------------------------------------------------
__global__ __launch_bounds__(256, 3) void qkv_gemm_kernel(
    const unsigned short* __restrict__ A0, const unsigned short* __restrict__ A1,
    const unsigned short* __restrict__ WtAll,
    const float* __restrict__ bq, const float* __restrict__ bk0,
    const float* __restrict__ bv0, const float* __restrict__ bk1,
    const float* __restrict__ bv1,
    unsigned short* __restrict__ qb, unsigned short* __restrict__ kb0,
    unsigned short* __restrict__ vb0, unsigned short* __restrict__ kb1,
    unsigned short* __restrict__ vb1,
    float* __restrict__ ks0, float* __restrict__ ks1) {
    __shared__ unsigned short As[2][128][64];   // 32 KB, linear (gload_lds dest)
    int t = threadIdx.x;
    int row0 = blockIdx.x * 128;
    int y = blockIdx.y;

    const unsigned short* A;
    const unsigned short* Btw;
    const float* bsel; unsigned short* osel; bool sm; float* ksp;
    int colIn;
    if (y < 6) {
        A = A0; int wid = y >> 1; colIn = (y & 1) * 128;
        Btw = WtAll + (size_t)wid * 65536;
        if (wid == 0)      { bsel = bq;  osel = qb;  sm = true;  ksp = nullptr; }
        else if (wid == 1) { bsel = bk0; osel = kb0; sm = true;  ksp = ks0; }
        else               { bsel = bv0; osel = vb0; sm = false; ksp = nullptr; }
    } else {
        int y2 = y - 6;
        A = A1; int wid = y2 >> 1; colIn = (y2 & 1) * 128;
        Btw = WtAll + (size_t)(3 + wid) * 65536;
        if (wid == 0)      { bsel = bk1; osel = kb1; sm = true;  ksp = ks1; }
        else               { bsel = bv1; osel = vb1; sm = false; ksp = nullptr; }
    }

    int lane = t & 63, w = t >> 6;
    int wr = w >> 1, wc = w & 1;
    int frow = lane & 15, fk = (lane >> 4) * 8;

    int srow_in_g = lane >> 3;            // 0..7
    int schunk = lane & 7;                // 16B chunk within 128B row
    auto stageA = [&](int kt, int bf) {
#pragma unroll
        for (int i = 0; i < 4; ++i) {
            int g = w * 4 + i;
            int r = g * 8 + srow_in_g;
            int c = schunk ^ (r & 7);     // pre-swizzled source chunk
            const unsigned short* src = A + (long long)(row0 + r) * Cn + kt * 64 + c * 8;
            GLOAD_LDS16(src, &As[bf][g * 8][0]);
        }
    };

    f32x4 acc[4][4];
#pragma unroll
    for (int m = 0; m < 4; ++m)
#pragma unroll
        for (int n = 0; n < 4; ++n) {
            acc[m][n][0] = 0.f; acc[m][n][1] = 0.f;
            acc[m][n][2] = 0.f; acc[m][n][3] = 0.f;
        }

    stageA(0, 0);
    int bf = 0;
#pragma unroll
    for (int kt = 0; kt < 4; ++kt) {
        // B fragments for this kt (8 loads; wave col base = colIn + wc*64)
        bf16x8 bfr[2][4];
#pragma unroll
        for (int ks = 0; ks < 2; ++ks)
#pragma unroll
            for (int n = 0; n < 4; ++n)
                bfr[ks][n] = *(const bf16x8*)(
                    Btw + (long long)(colIn + wc * 64 + n * 16 + frow) * Cn
                        + kt * 64 + ks * 32 + fk);
        if (kt < 3) {
            stageA(kt + 1, bf ^ 1);
            asm volatile("s_waitcnt vmcnt(4)" ::: "memory");   // stage(kt) retired
        } else {
            asm volatile("s_waitcnt vmcnt(0)" ::: "memory");
        }
        __builtin_amdgcn_s_barrier();
#pragma unroll
        for (int ks = 0; ks < 2; ++ks) {
#pragma unroll
            for (int m = 0; m < 4; ++m) {
                int arow = wr * 64 + m * 16 + frow;
                bf16x8 afr = *(const bf16x8*)&As[bf][arow][(ks * 32 + fk) ^ ((arow & 7) << 3)];
#pragma unroll
                for (int n = 0; n < 4; ++n)
                    acc[m][n] = __builtin_amdgcn_mfma_f32_16x16x32_bf16(afr, bfr[ks][n],
                                                                        acc[m][n], 0, 0, 0);
            }
        }
        __builtin_amdgcn_s_barrier();
        bf ^= 1;
    }

    if (sm) {
        int colA = colIn + wc * 64 + frow;       // heads: (n0,n1) and (n2,n3)
        float b0 = bsel[colA], b1 = bsel[colA + 16];
        float b2 = bsel[colA + 32], b3 = bsel[colA + 48];
        float ps0 = 0.f, ps1 = 0.f, ps2 = 0.f, ps3 = 0.f;
#pragma unroll
        for (int m = 0; m < 4; ++m) {
            int rbase = row0 + wr * 64 + m * 16 + (lane >> 4) * 4;
#pragma unroll
            for (int r = 0; r < 4; ++r) {
                float e0 = __expf(acc[m][0][r] + b0);
                float e1 = __expf(acc[m][1][r] + b1);
                float e2 = __expf(acc[m][2][r] + b2);
                float e3 = __expf(acc[m][3][r] + b3);
                float s01 = e0 + e1, s23 = e2 + e3;
#pragma unroll
                for (int msk = 1; msk < 16; msk <<= 1) {
                    s01 += __shfl_xor(s01, msk);
                    s23 += __shfl_xor(s23, msk);
                }
                float i01 = 1.0f / s01, i23 = 1.0f / s23;
                e0 *= i01; e1 *= i01; e2 *= i23; e3 *= i23;
                long long idx = (long long)(rbase + r) * Cn + colA;
                osel[idx]      = f2bf(e0);
                osel[idx + 16] = f2bf(e1);
                osel[idx + 32] = f2bf(e2);
                osel[idx + 48] = f2bf(e3);
                ps0 += e0; ps1 += e1; ps2 += e2; ps3 += e3;
            }
        }
        if (ksp) {
            ps0 += __shfl_xor(ps0, 16); ps0 += __shfl_xor(ps0, 32);
            ps1 += __shfl_xor(ps1, 16); ps1 += __shfl_xor(ps1, 32);
            ps2 += __shfl_xor(ps2, 16); ps2 += __shfl_xor(ps2, 32);
            ps3 += __shfl_xor(ps3, 16); ps3 += __shfl_xor(ps3, 32);
            if (lane < 16) {
                int b = row0 >> 13;
                int c0a = colA, c1a = colA + 16, c2a = colA + 32, c3a = colA + 48;
                atomicAdd(ksp + (b * 8 + (c0a >> 5)) * 32 + (c0a & 31), ps0);
                atomicAdd(ksp + (b * 8 + (c1a >> 5)) * 32 + (c1a & 31), ps1);
                atomicAdd(ksp + (b * 8 + (c2a >> 5)) * 32 + (c2a & 31), ps2);
                atomicAdd(ksp + (b * 8 + (c3a >> 5)) * 32 + (c3a & 31), ps3);
            }
        }
    } else {
#pragma unroll
        for (int m = 0; m < 4; ++m) {
            int rbase = row0 + wr * 64 + m * 16 + (lane >> 4) * 4;
#pragma unroll
            for (int n = 0; n < 4; ++n) {
                int col = colIn + wc * 64 + n * 16 + frow;
                float bv = bsel[col];
#pragma unroll
                for (int r = 0; r < 4; ++r) {
                    long long idx = (long long)(rbase + r) * Cn + col;
                    osel[idx] = f2bf(acc[m][n][r] + bv);
                }
            }
        }
    }
}

// ---------------------------------------------------------------------------
// Tail GEMM (r17 body).  EPI: 0 plain->bf16, 1 GELU(sigmoid)->bf16,
// 2 +resid->fp32, 3 +resid->fp32 & bf16(x*softplus(mu)), 4 LeakyReLU->fp32
// with per-batch Bt.
// ---------------------------------------------------------------------------
template <int EPI>
__global__ __launch_bounds__(256, 4) void gemm_kernel(
    const unsigned short* __restrict__ A, const unsigned short* __restrict__ Bt,
    const float* __restrict__ bias, float* __restrict__ outF,
    const float* __restrict__ resid, unsigned short* __restrict__ outB,
    unsigned short* __restrict__ outB2, const float* __restrict__ mu) {
    __shared__ unsigned short As[2][128][64];   // 32 KB, linear (gload_lds dest)
    int t = threadIdx.x;
    int row0 = blockIdx.x * 128;
    int col0 = blockIdx.y * 64;
    if (EPI == 4) Bt += (size_t)(row0 >> 13) * Cn * Cn;   // per-batch B
    int lane = t & 63, w = t >> 6;
    int wr = w >> 1, wc = w & 1;
    int frow = lane & 15, fk = (lane >> 4) * 8;

    bf16x8 bfr[4][2][2];
#pragma unroll
    for (int kt = 0; kt < 4; ++kt)
#pragma unroll
        for (int ks = 0; ks < 2; ++ks)
#pragma unroll
            for (int n = 0; n < 2; ++n)
                bfr[kt][ks][n] = *(const bf16x8*)(
                    Bt + (long long)(col0 + wc * 32 + n * 16 + frow) * Cn
                       + kt * 64 + ks * 32 + fk);

    int srow_in_g = lane >> 3;
    int schunk = lane & 7;
    auto stageA = [&](int kt, int bf) {
#pragma unroll
        for (int i = 0; i < 4; ++i) {
            int g = w * 4 + i;
            int r = g * 8 + srow_in_g;
            int c = schunk ^ (r & 7);
            const unsigned short* src = A + (long long)(row0 + r) * Cn + kt * 64 + c * 8;
            GLOAD_LDS16(src, &As[bf][g * 8][0]);
        }
    };

    f32x4 acc[4][2];
#pragma unroll
    for (int m = 0; m < 4; ++m)
#pragma unroll
        for (int n = 0; n < 2; ++n) {
            acc[m][n][0] = 0.f; acc[m][n][1] = 0.f;
            acc[m][n][2] = 0.f; acc[m][n][3] = 0.f;
        }

    stageA(0, 0);
    int bf = 0;
#pragma unroll
    for (int kt = 0; kt < 4; ++kt) {
        if (kt < 3) {
            stageA(kt + 1, bf ^ 1);
            asm volatile("s_waitcnt vmcnt(4)" ::: "memory");
        } else {
            asm volatile("s_waitcnt vmcnt(0)" ::: "memory");
        }
        __builtin_amdgcn_s_barrier();
#pragma unroll
        for (int ks = 0; ks < 2; ++ks) {
#pragma unroll
            for (int m = 0; m < 4; ++m) {
                int arow = wr * 64 + m * 16 + frow;
                bf16x8 afr = *(const bf16x8*)&As[bf][arow][(ks * 32 + fk) ^ ((arow & 7) << 3)];
#pragma unroll
                for (int n = 0; n < 2; ++n)
                    acc[m][n] = __builtin_amdgcn_mfma_f32_16x16x32_bf16(afr, bfr[kt][ks][n],
                                                                        acc[m][n], 0, 0, 0);
            }
        }
        __builtin_amdgcn_s_barrier();
        bf ^= 1;
    }

    float spv[2];
    if (EPI == 3) {
#pragma unroll
        for (int n = 0; n < 2; ++n) {
            float m_ = mu[col0 + wc * 32 + n * 16 + frow];
            spv[n] = (m_ > 20.f) ? m_ : log1pf(expf(m_));
        }
    }
#pragma unroll
    for (int m = 0; m < 4; ++m) {
        int rbase = row0 + wr * 64 + m * 16 + (lane >> 4) * 4;
#pragma unroll
        for (int n = 0; n < 2; ++n) {
            int col = col0 + wc * 32 + n * 16 + frow;
            float bv = (EPI == 4) ? 0.0f : bias[col];
#pragma unroll
            for (int r = 0; r < 4; ++r) {
                long long idx = (long long)(rbase + r) * Cn + col;
                float v = acc[m][n][r] + bv;
                if (EPI == 0) {
                    outB[idx] = f2bf(v);
                } else if (EPI == 1) {
                    float sg = 1.0f / (1.0f + __expf(-1.702f * v));
                    outB[idx] = f2bf(v * sg);
                } else if (EPI == 2) {
                    outF[idx] = v + resid[idx];
                } else if (EPI == 3) {
                    float xv = v + resid[idx];
                    outF[idx] = xv;
                    outB2[idx] = f2bf(xv * spv[n]);
                } else {
                    outF[idx] = (v >= 0.0f) ? v : 0.01f * v;
                }
            }
        }
    }
}

// ---------------------------------------------------------------------------
// kv_gemm (MFMA) for BOTH streams: grid (32, 32, 2); z selects stream.
// ---------------------------------------------------------------------------
__global__ __launch_bounds__(256) void kv_gemm_kernel(
    const unsigned short* __restrict__ kbs0, const unsigned short* __restrict__ vbs0,
    float* __restrict__ kv0p,
    const unsigned short* __restrict__ kbs1, const unsigned short* __restrict__ vbs1,
    float* __restrict__ kv1p) {
    const unsigned short* kb = blockIdx.z ? kbs1 : kbs0;
    const unsigned short* vb = blockIdx.z ? vbs1 : vbs0;
    float* kv = blockIdx.z ? kv1p : kv0p;
    __shared__ unsigned short kl[256][36];
    __shared__ unsigned short vl[256][36];
    __shared__ float red[4][1024];
    int bh = blockIdx.x, b = bh >> 3, h = bh & 7;
    int n0 = blockIdx.y * 256;
    int t = threadIdx.x, lane = t & 63, w = t >> 6;
    {
        int r0 = t >> 2, ch = (t & 3) * 8;
        long long gbase = ((long long)(b * Nn + n0)) * Cn + h * Dn + ch;
#pragma unroll
        for (int i = 0; i < 4; ++i) {
            int r = r0 + i * 64;
            ushortx8 dk = *(const ushortx8*)(kb + gbase + (long long)r * Cn);
            ushortx8 dv = *(const ushortx8*)(vb + gbase + (long long)r * Cn);
            ushortx4 k0 = {dk[0], dk[1], dk[2], dk[3]};
            ushortx4 k1 = {dk[4], dk[5], dk[6], dk[7]};
            ushortx4 v0 = {dv[0], dv[1], dv[2], dv[3]};
            ushortx4 v1 = {dv[4], dv[5], dv[6], dv[7]};
            *(ushortx4*)&kl[r][ch]     = k0;
            *(ushortx4*)&kl[r][ch + 4] = k1;
            *(ushortx4*)&vl[r][ch]     = v0;
            *(ushortx4*)&vl[r][ch + 4] = v1;
        }
    }
    __syncthreads();
    int frow = lane & 15, fk = (lane >> 4) * 8;
    f32x4 acc[2][2];
#pragma unroll
    for (int m = 0; m < 2; ++m)
#pragma unroll
        for (int n = 0; n < 2; ++n) {
            acc[m][n][0] = 0.f; acc[m][n][1] = 0.f;
            acc[m][n][2] = 0.f; acc[m][n][3] = 0.f;
        }
    int nb = w * 64;
#pragma unroll
    for (int s = 0; s < 2; ++s) {
        int kk = nb + s * 32 + fk;
        bf16x8 a0, a1, b0, b1;
#pragma unroll
        for (int j = 0; j < 8; ++j) {
            a0[j] = (short)kl[kk + j][frow];
            a1[j] = (short)kl[kk + j][16 + frow];
            b0[j] = (short)vl[kk + j][frow];
            b1[j] = (short)vl[kk + j][16 + frow];
        }
        acc[0][0] = __builtin_amdgcn_mfma_f32_16x16x32_bf16(a0, b0, acc[0][0], 0, 0, 0);
        acc[0][1] = __builtin_amdgcn_mfma_f32_16x16x32_bf16(a0, b1, acc[0][1], 0, 0, 0);
        acc[1][0] = __builtin_amdgcn_mfma_f32_16x16x32_bf16(a1, b0, acc[1][0], 0, 0, 0);
        acc[1][1] = __builtin_amdgcn_mfma_f32_16x16x32_bf16(a1, b1, acc[1][1], 0, 0, 0);
    }
#pragma unroll
    for (int m = 0; m < 2; ++m)
#pragma unroll
        for (int n = 0; n < 2; ++n)
#pragma unroll
            for (int r = 0; r < 4; ++r)
                red[w][(m * 16 + (lane >> 4) * 4 + r) * 32 + n * 16 + frow] = acc[m][n][r];
    __syncthreads();
    float* out = kv + (long long)bh * 1024;
#pragma unroll
    for (int i = 0; i < 4; ++i) {
        int idx = t + i * 256;
        atomicAdd(out + idx, red[0][idx] + red[1][idx] + red[2][idx] + red[3][idx]);
    }
}

// ---------------------------------------------------------------------------
// attn epilogue (MFMA): out[128,32] = q + (q@KV0)*dinv0 + (q@KV1)*dinv1.
// ---------------------------------------------------------------------------
__global__ __launch_bounds__(256) void attn_out_kernel(
    const unsigned short* __restrict__ qb, const float* __restrict__ kv0,
    const float* __restrict__ ks0, const float* __restrict__ kv1,
    const float* __restrict__ ks1, unsigned short* __restrict__ outb) {
    __shared__ unsigned short BT[80][40];   // [col][k], padded stride 80B
    int bh = blockIdx.y;
    int b = bh >> 3, h = bh & 7;
    int n0 = blockIdx.x * 128;
    int t = threadIdx.x;
    {
        int e = t & 31, d0 = t >> 5;
        const float* KV0 = kv0 + (long long)bh * 1024;
        const float* KV1 = kv1 + (long long)bh * 1024;
#pragma unroll
        for (int i = 0; i < 4; ++i) {
            int d = d0 + 8 * i;
            BT[e][d]      = f2bf(KV0[d * 32 + e]);
            BT[32 + e][d] = f2bf(KV1[d * 32 + e]);
        }
        if (t < 32)            BT[64][t]      = f2bf(ks0[bh * 32 + t]);
        else if (t < 64)       BT[65][t - 32] = f2bf(ks1[bh * 32 + (t - 32)]);
        if (t < 224) {
            int c = 66 + (t >> 4), k2 = (t & 15) * 2;
            BT[c][k2] = 0; BT[c][k2 + 1] = 0;
        }
    }
    __syncthreads();

    int lane = t & 63, w = t >> 6;
    int frow = lane & 15, fk = (lane >> 4) * 8;
    bf16x8 bfr[5];
#pragma unroll
    for (int n = 0; n < 5; ++n)
        bfr[n] = *(const bf16x8*)&BT[n * 16 + frow][fk];

    f32x4 acc[2][5];
#pragma unroll
    for (int m = 0; m < 2; ++m)
#pragma unroll
        for (int n = 0; n < 5; ++n) {
            acc[m][n][0] = 0.f; acc[m][n][1] = 0.f;
            acc[m][n][2] = 0.f; acc[m][n][3] = 0.f;
        }
    long long grow0 = (long long)b * Nn + n0 + w * 32;
#pragma unroll
    for (int m = 0; m < 2; ++m) {
        bf16x8 afr = *(const bf16x8*)(qb + (grow0 + m * 16 + frow) * Cn + h * Dn + fk);
#pragma unroll
        for (int n = 0; n < 5; ++n)
            acc[m][n] = __builtin_amdgcn_mfma_f32_16x16x32_bf16(afr, bfr[n],
                                                                acc[m][n], 0, 0, 0);
    }
#pragma unroll
    for (int m = 0; m < 2; ++m) {
#pragma unroll
        for (int r = 0; r < 4; ++r) {
            float s0 = __shfl(acc[m][4][r], lane & 48, 64);
            float s1 = __shfl(acc[m][4][r], (lane & 48) + 1, 64);
            float inv0 = 1.0f / s0, inv1 = 1.0f / s1;
            long long row = grow0 + m * 16 + (lane >> 4) * 4 + r;
            long long base = row * Cn + h * Dn + (lane & 15);
            float q0 = bf2f(qb[base]), q1 = bf2f(qb[base + 16]);
            outb[base]      = f2bf(q0 + acc[m][0][r] * inv0 + acc[m][2][r] * inv1);
            outb[base + 16] = f2bf(q1 + acc[m][1][r] * inv0 + acc[m][3][r] * inv1);
        }
    }
}

// ---------------------------------------------------------------------------
// Batched transpose + bf16 cast:  out[b][c][n] = bf16(in[b][n][c]).
// ---------------------------------------------------------------------------
__global__ __launch_bounds__(256) void transpose_cast_kernel(
    const float* __restrict__ in, unsigned short* __restrict__ out) {
    __shared__ float tile[64][33];
    int b = blockIdx.z;
    int n0 = blockIdx.x * 64;
    int c0 = blockIdx.y * 32;
    int t = threadIdx.x;
    int r = t >> 2;
    int cc = (t & 3) * 8;
    const float* src = in + ((long long)b * Nn + n0 + r) * Cn + c0 + cc;
    float4 a0 = *(const float4*)src;
    float4 a1 = *(const float4*)(src + 4);
    tile[r][cc + 0] = a0.x; tile[r][cc + 1] = a0.y;
    tile[r][cc + 2] = a0.z; tile[r][cc + 3] = a0.w;
    tile[r][cc + 4] = a1.x; tile[r][cc + 5] = a1.y;
    tile[r][cc + 6] = a1.z; tile[r][cc + 7] = a1.w;
    __syncthreads();
    int c = t >> 3;
    int nn = (t & 7) * 8;
    ushortx8 o;
#pragma unroll
    for (int j = 0; j < 8; ++j) o[j] = f2bf(tile[nn + j][c]);
    *(ushortx8*)(out + ((long long)b * Cn + c0 + c) * Nn + n0 + nn) = o;
}

// ---------------------------------------------------------------------------
// Split-K bilinear GEMM: xtfxT[b][f][c] += sum_{k-range} fxT[b][f][k]*xT[b][c][k]
// 16 splits of K=512.  grid (2, 4, 64).
// ---------------------------------------------------------------------------
__global__ __launch_bounds__(256, 2) void bilin_gemm_kernel(
    const unsigned short* __restrict__ A, const unsigned short* __restrict__ Bm,
    float* __restrict__ Cacc) {
    __shared__ unsigned short As[128][72];
    __shared__ unsigned short Bs[64][72];
    int t = threadIdx.x;
    int b = blockIdx.z >> 4;
    int split = blockIdx.z & 15;
    int row0 = blockIdx.x * 128;   // f
    int col0 = blockIdx.y * 64;    // c
    const unsigned short* Ab = A + (long long)b * Cn * Nn;
    const unsigned short* Bb = Bm + (long long)b * Cn * Nn;
    int lane = t & 63, w = t >> 6;
    int wr = w >> 1, wc = w & 1;
    int frow = lane & 15, fk = (lane >> 4) * 8;
    f32x4 acc[4][2];
#pragma unroll
    for (int m = 0; m < 4; ++m)
#pragma unroll
        for (int n = 0; n < 2; ++n) {
            acc[m][n][0] = 0.f; acc[m][n][1] = 0.f;
            acc[m][n][2] = 0.f; acc[m][n][3] = 0.f;
        }
    int sr = t >> 3, sc = (t & 7) * 8;
    for (int kt = 0; kt < 8; ++kt) {
        int k0 = split * 512 + kt * 64;
#pragma unroll
        for (int p = 0; p < 4; ++p) {
            int rr = sr + p * 32;
            ushortx8 d = *(const ushortx8*)(Ab + (long long)(row0 + rr) * Nn + k0 + sc);
            *(ushortx8*)&As[rr][sc] = d;
        }
#pragma unroll
        for (int p = 0; p < 2; ++p) {
            int br = sr + p * 32;
            ushortx8 d = *(const ushortx8*)(Bb + (long long)(col0 + br) * Nn + k0 + sc);
            *(ushortx8*)&Bs[br][sc] = d;
        }
        __syncthreads();
#pragma unroll
        for (int ks = 0; ks < 2; ++ks) {
            bf16x8 bfr[2];
#pragma unroll
            for (int n = 0; n < 2; ++n)
                bfr[n] = *(const bf16x8*)&Bs[wc * 32 + n * 16 + frow][ks * 32 + fk];
#pragma unroll
            for (int m = 0; m < 4; ++m) {
                bf16x8 afr = *(const bf16x8*)&As[wr * 64 + m * 16 + frow][ks * 32 + fk];
#pragma unroll
                for (int n = 0; n < 2; ++n)
                    acc[m][n] = __builtin_amdgcn_mfma_f32_16x16x32_bf16(afr, bfr[n],
                                                                        acc[m][n], 0, 0, 0);
            }
        }
        __syncthreads();
    }
    float* base = Cacc + (long long)b * Cn * Cn;
#pragma unroll
    for (int m = 0; m < 4; ++m) {
        int rbase = row0 + wr * 64 + m * 16 + (lane >> 4) * 4;
#pragma unroll
        for (int n = 0; n < 2; ++n) {
            int col = col0 + wc * 32 + n * 16 + frow;
#pragma unroll
            for (int r = 0; r < 4; ++r)
                atomicAdd(base + (long long)(rbase + r) * Cn + col, acc[m][n][r]);
        }
    }
}

// fp32 -> bf16 cast, 4 elems/thread.
__global__ __launch_bounds__(256) void castf2b_kernel(const float* __restrict__ in,
                                                      unsigned short* __restrict__ out) {
    int i = (blockIdx.x * 256 + threadIdx.x) * 4;
    float4 v = *(const float4*)(in + i);
    ushortx4 o;
    o.x = f2bf(v.x); o.y = f2bf(v.y); o.z = f2bf(v.z); o.w = f2bf(v.w);
    *(ushortx4*)(out + i) = o;
}

// ---------------------------------------------------------------------------
extern "C" void kernel_launch(void* const* d_in, const int* in_sizes, int n_in,
                              void* d_out, int out_size, void* d_ws, size_t ws_size,
                              hipStream_t stream) {
    const float* input  = (const float*)d_in[0];
    const float* fx     = (const float*)d_in[1];
    const float* inputf = (const float*)d_in[2];
    const float* ln1g = (const float*)d_in[3],  *ln1b = (const float*)d_in[4];
    const float* ln2g = (const float*)d_in[5],  *ln2b = (const float*)d_in[6];
    const float* ln3g = (const float*)d_in[7],  *ln3b = (const float*)d_in[8];
    const float* Wq  = (const float*)d_in[9],   *bq  = (const float*)d_in[10];
    const float* Wk0 = (const float*)d_in[11],  *bk0 = (const float*)d_in[12];
    const float* Wv0 = (const float*)d_in[13],  *bv0 = (const float*)d_in[14];
    const float* Wk1 = (const float*)d_in[15],  *bk1 = (const float*)d_in[16];
    const float* Wv1 = (const float*)d_in[17],  *bv1 = (const float*)d_in[18];
    const float* Wo  = (const float*)d_in[19],  *bo  = (const float*)d_in[20];
    const float* Wm1 = (const float*)d_in[21],  *bm1 = (const float*)d_in[22];
    const float* Wm2 = (const float*)d_in[23],  *bm2 = (const float*)d_in[24];
    const float* mu  = (const float*)d_in[25];

    float* xOut  = (float*)d_out;        // output 0: x
    float* fxOut = xOut + S;             // output 1: fx_new

    char* ws = (char*)d_ws;
    const size_t SB = (size_t)S * 2;     // 16 MB bf16 buffer
    unsigned short* x1b  = (unsigned short*)(ws + 0 * SB);
    unsigned short* f1b  = (unsigned short*)(ws + 1 * SB);
    unsigned short* qb   = (unsigned short*)(ws + 2 * SB);
    unsigned short* kb   = (unsigned short*)(ws + 3 * SB);
    unsigned short* vb   = (unsigned short*)(ws + 4 * SB);
    unsigned short* outb = (unsigned short*)(ws + 5 * SB);
    unsigned short* kb2  = (unsigned short*)(ws + 6 * SB);
    unsigned short* vb2  = (unsigned short*)(ws + 7 * SB);
    unsigned short* Wt   = (unsigned short*)(ws + 8 * SB);               // 8 x 64K bf16
    unsigned short* xtT  = (unsigned short*)(ws + 8 * SB + (size_t)8 * 65536 * 2);
    float* zbase = (float*)(ws + 8 * SB + (size_t)8 * 65536 * 2 + (size_t)Bn * 65536 * 2);
    float* kv0   = zbase;                 // 32768
    float* kv1   = zbase + 32768;         // 32768
    float* ks0   = zbase + 65536;         // 1024
    float* ks1   = zbase + 66560;         // 1024
    float* xtfxT = zbase + 67584;         // 262144  [b][f][c]
    const size_t ZFLOATS = 67584 + 262144;

    hipMemsetAsync(zbase, 0, ZFLOATS * sizeof(float), stream);

    wtrans_all_kernel<<<dim3(8, 8), 256, 0, stream>>>(Wq, Wk0, Wv0, Wk1, Wv1, Wo, Wm1, Wm2, Wt);

    peln2_kernel<<<dim3(BN / 4, 2), 256, 0, stream>>>(input, ln1g, ln1b, x1b,
                                                      inputf, ln2g, ln2b, f1b);

    // ALL 5 QKV GEMMs in one dispatch (both streams), 128x128 tiles
    qkv_gemm_kernel<<<dim3(BN / 128, 10), 256, 0, stream>>>(
        f1b, x1b, Wt, bq, bk0, bv0, bk1, bv1,
        qb, kb, vb, kb2, vb2, ks0, ks1);
    // both kv reductions in one dispatch
    kv_gemm_kernel<<<dim3(32, 32, 2), 256, 0, stream>>>(kb, vb, kv0, kb2, vb2, kv1);

    attn_out_kernel<<<dim3(Nn / 128, Bn * Hn), 256, 0, stream>>>(qb, kv0, ks0, kv1, ks1, outb);

    dim3 ggrid(BN / 128, 4);
    // x = out @ Wo + bo + input   -> d_out[0] (fp32)
    gemm_kernel<2><<<ggrid, 256, 0, stream>>>(outb, Wt + (size_t)5 * 65536, bo,
                                              xOut, input, nullptr, nullptr, nullptr);
    // MLP
    ln_kernel<<<BN / 4, 256, 0, stream>>>(xOut, ln3g, ln3b, f1b);
    gemm_kernel<1><<<ggrid, 256, 0, stream>>>(f1b, Wt + (size_t)6 * 65536, bm1,
                                              nullptr, nullptr, x1b, nullptr, nullptr);
    gemm_kernel<3><<<ggrid, 256, 0, stream>>>(x1b, Wt + (size_t)7 * 65536, bm2,
                                              xOut, xOut, nullptr, qb, mu);

    // bilinear fx update
    transpose_cast_kernel<<<dim3(Nn / 64, Cn / 32, Bn), 256, 0, stream>>>(xOut, kb);  // xT
    transpose_cast_kernel<<<dim3(Nn / 64, Cn / 32, Bn), 256, 0, stream>>>(fx,   vb);  // fxT
    bilin_gemm_kernel<<<dim3(2, 4, 64), 256, 0, stream>>>(vb, kb, xtfxT);
    castf2b_kernel<<<(int)(Bn * 65536 / 1024), 256, 0, stream>>>(xtfxT, xtT);
    gemm_kernel<4><<<ggrid, 256, 0, stream>>>(qb, xtT, nullptr,
                                              fxOut, nullptr, nullptr, nullptr, nullptr);
}

// Round 20
// 269.671 us; speedup vs baseline: 1.0592x; 1.0047x over previous
//
#include <hip/hip_runtime.h>

// ---------------------------------------------------------------------------
// ONOBlock forward, MI355X (gfx950).  B=4, N=8192, C=256, H=8, D=32.
// fp32 in/out; bf16 MFMA internally (tolerance is 2% of absmax).
// r19 baseline (270.9us, best) + ONE knob: qkv launch_bounds 3->4
// (VGPR=72 fits bound-4's 128 budget; raises residency 3->4 blocks/CU).
// ---------------------------------------------------------------------------

typedef __attribute__((ext_vector_type(8))) short    bf16x8;   // MFMA A/B frag
typedef __attribute__((ext_vector_type(4))) float    f32x4;    // MFMA C/D frag
typedef __attribute__((ext_vector_type(8))) unsigned short ushortx8;
typedef __attribute__((ext_vector_type(4))) unsigned short ushortx4;

static constexpr int Bn = 4, Nn = 8192, Cn = 256, Hn = 8, Dn = 32;
static constexpr int BN = Bn * Nn;                        // 32768 rows
static constexpr long long S = (long long)BN * Cn;        // 8388608 elems/tensor

#define DEVI __device__ __forceinline__

// async global->LDS, 16B per lane; dest = lds_base + lane*16 (wave-uniform base)
#define GLOAD_LDS16(gsrc, ldst)                                                  \
    __builtin_amdgcn_global_load_lds(                                            \
        (const __attribute__((address_space(1))) unsigned int*)(gsrc),           \
        (__attribute__((address_space(3))) unsigned int*)(ldst), 16, 0, 0)

DEVI unsigned short f2bf(float f) {
    unsigned int u = __builtin_bit_cast(unsigned int, f);
    u += 0x7fffu + ((u >> 16) & 1u);          // RNE
    return (unsigned short)(u >> 16);
}
DEVI float bf2f(unsigned short h) {
    unsigned int u = ((unsigned int)h) << 16;
    return __builtin_bit_cast(float, u);
}

// ---------------------------------------------------------------------------
// Weight transpose + bf16 cast for all 8 weights in one launch.
// ---------------------------------------------------------------------------
__global__ __launch_bounds__(256) void wtrans_all_kernel(
    const float* __restrict__ W0, const float* __restrict__ W1,
    const float* __restrict__ W2, const float* __restrict__ W3,
    const float* __restrict__ W4, const float* __restrict__ W5,
    const float* __restrict__ W6, const float* __restrict__ W7,
    unsigned short* __restrict__ WtAll) {
    __shared__ float tile[256][33];
    const float* W;
    switch (blockIdx.y) {
        case 0: W = W0; break; case 1: W = W1; break;
        case 2: W = W2; break; case 3: W = W3; break;
        case 4: W = W4; break; case 5: W = W5; break;
        case 6: W = W6; break; default: W = W7; break;
    }
    unsigned short* Wt = WtAll + (size_t)blockIdx.y * 65536;
    int t = threadIdx.x;
    int j0 = blockIdx.x * 32;
#pragma unroll
    for (int p = 0; p < 32; ++p) {
        int k = p * 8 + (t >> 5);
        tile[k][t & 31] = W[k * Cn + j0 + (t & 31)];
    }
    __syncthreads();
#pragma unroll
    for (int p = 0; p < 8; ++p) {
        int j = p * 4 + (t >> 6);
        int k0 = (t & 63) * 4;
        ushortx4 o;
        o.x = f2bf(tile[k0 + 0][j]);
        o.y = f2bf(tile[k0 + 1][j]);
        o.z = f2bf(tile[k0 + 2][j]);
        o.w = f2bf(tile[k0 + 3][j]);
        *(ushortx4*)(Wt + (long long)(j0 + j) * Cn + k0) = o;
    }
}

// ---------------------------------------------------------------------------
// PE + LayerNorm for both streams in one launch (grid.y selects stream).
// ---------------------------------------------------------------------------
__global__ __launch_bounds__(256) void peln2_kernel(
    const float* __restrict__ in0, const float* __restrict__ g0, const float* __restrict__ b0,
    unsigned short* __restrict__ o0,
    const float* __restrict__ in1, const float* __restrict__ g1, const float* __restrict__ b1,
    unsigned short* __restrict__ o1) {
    const float* in  = blockIdx.y ? in1 : in0;
    const float* gam = blockIdx.y ? g1 : g0;
    const float* bet = blockIdx.y ? b1 : b0;
    unsigned short* outb = blockIdx.y ? o1 : o0;
    int r = blockIdx.x * 4 + (threadIdx.x >> 6);
    int lane = threadIdx.x & 63;
    int n = r & (Nn - 1);
    int c0 = lane * 4;
    const float* rowp = in + (long long)r * Cn + c0;
    float v0 = rowp[0], v1 = rowp[1], v2 = rowp[2], v3 = rowp[3];
    const float Kf = 0.07195578415606394f;   // ln(10000)/128
    float fn = (float)n;
    float ang0 = fn * expf(-Kf * (float)(2 * lane));
    float ang1 = fn * expf(-Kf * (float)(2 * lane + 1));
    v0 += sinf(ang0); v1 += cosf(ang0);
    v2 += sinf(ang1); v3 += cosf(ang1);
    float s = v0 + v1 + v2 + v3;
#pragma unroll
    for (int m = 1; m < 64; m <<= 1) s += __shfl_xor(s, m, 64);
    float mean = s * (1.0f / 256.0f);
    float d0 = v0 - mean, d1 = v1 - mean, d2 = v2 - mean, d3 = v3 - mean;
    float q = d0 * d0 + d1 * d1 + d2 * d2 + d3 * d3;
#pragma unroll
    for (int m = 1; m < 64; m <<= 1) q += __shfl_xor(q, m, 64);
    float rstd = rsqrtf(q * (1.0f / 256.0f) + 1e-6f);
    float4 g4 = *(const float4*)(gam + c0);
    float4 b4 = *(const float4*)(bet + c0);
    ushortx4 o;
    o.x = f2bf(d0 * rstd * g4.x + b4.x);
    o.y = f2bf(d1 * rstd * g4.y + b4.y);
    o.z = f2bf(d2 * rstd * g4.z + b4.z);
    o.w = f2bf(d3 * rstd * g4.w + b4.w);
    *(ushortx4*)(outb + (long long)r * Cn + c0) = o;
}

// LN only (no PE), fp32 input -> bf16 out (for LN3).
__global__ __launch_bounds__(256) void ln_kernel(const float* __restrict__ in,
                                                 const float* __restrict__ gam,
                                                 const float* __restrict__ bet,
                                                 unsigned short* __restrict__ outb) {
    int r = blockIdx.x * 4 + (threadIdx.x >> 6);
    int lane = threadIdx.x & 63;
    int c0 = lane * 4;
    const float* rowp = in + (long long)r * Cn + c0;
    float v0 = rowp[0], v1 = rowp[1], v2 = rowp[2], v3 = rowp[3];
    float s = v0 + v1 + v2 + v3;
#pragma unroll
    for (int m = 1; m < 64; m <<= 1) s += __shfl_xor(s, m, 64);
    float mean = s * (1.0f / 256.0f);
    float d0 = v0 - mean, d1 = v1 - mean, d2 = v2 - mean, d3 = v3 - mean;
    float q = d0 * d0 + d1 * d1 + d2 * d2 + d3 * d3;
#pragma unroll
    for (int m = 1; m < 64; m <<= 1) q += __shfl_xor(q, m, 64);
    float rstd = rsqrtf(q * (1.0f / 256.0f) + 1e-6f);
    float4 g4 = *(const float4*)(gam + c0);
    float4 b4 = *(const float4*)(bet + c0);
    ushortx4 o;
    o.x = f2bf(d0 * rstd * g4.x + b4.x);
    o.y = f2bf(d1 * rstd * g4.y + b4.y);
    o.z = f2bf(d2 * rstd * g4.z + b4.z);
    o.w = f2bf(d3 * rstd * g4.w + b4.w);
    *(ushortx4*)(outb + (long long)r * Cn + c0) = o;
}

// ---------------------------------------------------------------------------
// Fused QKV GEMM, 128x128 tiles, BOTH streams.  grid (BN/128, 10):
//   y in [0,6): f-stream: wid=y>>1 (0=q sm | 1=k0 sm+ks0 | 2=v0), col=(y&1)*128
//   y in [6,10): x-stream: wid=(y-6)>>1 (0=k1 sm+ks1 | 1=v1)
// Wave (2x2): 64 rows x 64 cols (4 n-frags).  B frags loaded per-kt (L2-hot).
// ---------------------------------------------------------------------------
__global__ __launch_bounds__(256, 4) void qkv_gemm_kernel(
    const unsigned short* __restrict__ A0, const unsigned short* __restrict__ A1,
    const unsigned short* __restrict__ WtAll,
    const float* __restrict__ bq, const float* __restrict__ bk0,
    const float* __restrict__ bv0, const float* __restrict__ bk1,
    const float* __restrict__ bv1,
    unsigned short* __restrict__ qb, unsigned short* __restrict__ kb0,
    unsigned short* __restrict__ vb0, unsigned short* __restrict__ kb1,
    unsigned short* __restrict__ vb1,
    float* __restrict__ ks0, float* __restrict__ ks1) {
    __shared__ unsigned short As[2][128][64];   // 32 KB, linear (gload_lds dest)
    int t = threadIdx.x;
    int row0 = blockIdx.x * 128;
    int y = blockIdx.y;

    const unsigned short* A;
    const unsigned short* Btw;
    const float* bsel; unsigned short* osel; bool sm; float* ksp;
    int colIn;
    if (y < 6) {
        A = A0; int wid = y >> 1; colIn = (y & 1) * 128;
        Btw = WtAll + (size_t)wid * 65536;
        if (wid == 0)      { bsel = bq;  osel = qb;  sm = true;  ksp = nullptr; }
        else if (wid == 1) { bsel = bk0; osel = kb0; sm = true;  ksp = ks0; }
        else               { bsel = bv0; osel = vb0; sm = false; ksp = nullptr; }
    } else {
        int y2 = y - 6;
        A = A1; int wid = y2 >> 1; colIn = (y2 & 1) * 128;
        Btw = WtAll + (size_t)(3 + wid) * 65536;
        if (wid == 0)      { bsel = bk1; osel = kb1; sm = true;  ksp = ks1; }
        else               { bsel = bv1; osel = vb1; sm = false; ksp = nullptr; }
    }

    int lane = t & 63, w = t >> 6;
    int wr = w >> 1, wc = w & 1;
    int frow = lane & 15, fk = (lane >> 4) * 8;

    int srow_in_g = lane >> 3;            // 0..7
    int schunk = lane & 7;                // 16B chunk within 128B row
    auto stageA = [&](int kt, int bf) {
#pragma unroll
        for (int i = 0; i < 4; ++i) {
            int g = w * 4 + i;
            int r = g * 8 + srow_in_g;
            int c = schunk ^ (r & 7);     // pre-swizzled source chunk
            const unsigned short* src = A + (long long)(row0 + r) * Cn + kt * 64 + c * 8;
            GLOAD_LDS16(src, &As[bf][g * 8][0]);
        }
    };

    f32x4 acc[4][4];
#pragma unroll
    for (int m = 0; m < 4; ++m)
#pragma unroll
        for (int n = 0; n < 4; ++n) {
            acc[m][n][0] = 0.f; acc[m][n][1] = 0.f;
            acc[m][n][2] = 0.f; acc[m][n][3] = 0.f;
        }

    stageA(0, 0);
    int bf = 0;
#pragma unroll
    for (int kt = 0; kt < 4; ++kt) {
        // B fragments for this kt (8 loads; wave col base = colIn + wc*64)
        bf16x8 bfr[2][4];
#pragma unroll
        for (int ks = 0; ks < 2; ++ks)
#pragma unroll
            for (int n = 0; n < 4; ++n)
                bfr[ks][n] = *(const bf16x8*)(
                    Btw + (long long)(colIn + wc * 64 + n * 16 + frow) * Cn
                        + kt * 64 + ks * 32 + fk);
        if (kt < 3) {
            stageA(kt + 1, bf ^ 1);
            asm volatile("s_waitcnt vmcnt(4)" ::: "memory");   // stage(kt) retired
        } else {
            asm volatile("s_waitcnt vmcnt(0)" ::: "memory");
        }
        __builtin_amdgcn_s_barrier();
#pragma unroll
        for (int ks = 0; ks < 2; ++ks) {
#pragma unroll
            for (int m = 0; m < 4; ++m) {
                int arow = wr * 64 + m * 16 + frow;
                bf16x8 afr = *(const bf16x8*)&As[bf][arow][(ks * 32 + fk) ^ ((arow & 7) << 3)];
#pragma unroll
                for (int n = 0; n < 4; ++n)
                    acc[m][n] = __builtin_amdgcn_mfma_f32_16x16x32_bf16(afr, bfr[ks][n],
                                                                        acc[m][n], 0, 0, 0);
            }
        }
        __builtin_amdgcn_s_barrier();
        bf ^= 1;
    }

    if (sm) {
        int colA = colIn + wc * 64 + frow;       // heads: (n0,n1) and (n2,n3)
        float b0 = bsel[colA], b1 = bsel[colA + 16];
        float b2 = bsel[colA + 32], b3 = bsel[colA + 48];
        float ps0 = 0.f, ps1 = 0.f, ps2 = 0.f, ps3 = 0.f;
#pragma unroll
        for (int m = 0; m < 4; ++m) {
            int rbase = row0 + wr * 64 + m * 16 + (lane >> 4) * 4;
#pragma unroll
            for (int r = 0; r < 4; ++r) {
                float e0 = __expf(acc[m][0][r] + b0);
                float e1 = __expf(acc[m][1][r] + b1);
                float e2 = __expf(acc[m][2][r] + b2);
                float e3 = __expf(acc[m][3][r] + b3);
                float s01 = e0 + e1, s23 = e2 + e3;
#pragma unroll
                for (int msk = 1; msk < 16; msk <<= 1) {
                    s01 += __shfl_xor(s01, msk);
                    s23 += __shfl_xor(s23, msk);
                }
                float i01 = 1.0f / s01, i23 = 1.0f / s23;
                e0 *= i01; e1 *= i01; e2 *= i23; e3 *= i23;
                long long idx = (long long)(rbase + r) * Cn + colA;
                osel[idx]      = f2bf(e0);
                osel[idx + 16] = f2bf(e1);
                osel[idx + 32] = f2bf(e2);
                osel[idx + 48] = f2bf(e3);
                ps0 += e0; ps1 += e1; ps2 += e2; ps3 += e3;
            }
        }
        if (ksp) {
            ps0 += __shfl_xor(ps0, 16); ps0 += __shfl_xor(ps0, 32);
            ps1 += __shfl_xor(ps1, 16); ps1 += __shfl_xor(ps1, 32);
            ps2 += __shfl_xor(ps2, 16); ps2 += __shfl_xor(ps2, 32);
            ps3 += __shfl_xor(ps3, 16); ps3 += __shfl_xor(ps3, 32);
            if (lane < 16) {
                int b = row0 >> 13;
                int c0a = colA, c1a = colA + 16, c2a = colA + 32, c3a = colA + 48;
                atomicAdd(ksp + (b * 8 + (c0a >> 5)) * 32 + (c0a & 31), ps0);
                atomicAdd(ksp + (b * 8 + (c1a >> 5)) * 32 + (c1a & 31), ps1);
                atomicAdd(ksp + (b * 8 + (c2a >> 5)) * 32 + (c2a & 31), ps2);
                atomicAdd(ksp + (b * 8 + (c3a >> 5)) * 32 + (c3a & 31), ps3);
            }
        }
    } else {
#pragma unroll
        for (int m = 0; m < 4; ++m) {
            int rbase = row0 + wr * 64 + m * 16 + (lane >> 4) * 4;
#pragma unroll
            for (int n = 0; n < 4; ++n) {
                int col = colIn + wc * 64 + n * 16 + frow;
                float bv = bsel[col];
#pragma unroll
                for (int r = 0; r < 4; ++r) {
                    long long idx = (long long)(rbase + r) * Cn + col;
                    osel[idx] = f2bf(acc[m][n][r] + bv);
                }
            }
        }
    }
}

// ---------------------------------------------------------------------------
// Tail GEMM (r17 body).  EPI: 0 plain->bf16, 1 GELU(sigmoid)->bf16,
// 2 +resid->fp32, 3 +resid->fp32 & bf16(x*softplus(mu)), 4 LeakyReLU->fp32
// with per-batch Bt.
// ---------------------------------------------------------------------------
template <int EPI>
__global__ __launch_bounds__(256, 4) void gemm_kernel(
    const unsigned short* __restrict__ A, const unsigned short* __restrict__ Bt,
    const float* __restrict__ bias, float* __restrict__ outF,
    const float* __restrict__ resid, unsigned short* __restrict__ outB,
    unsigned short* __restrict__ outB2, const float* __restrict__ mu) {
    __shared__ unsigned short As[2][128][64];   // 32 KB, linear (gload_lds dest)
    int t = threadIdx.x;
    int row0 = blockIdx.x * 128;
    int col0 = blockIdx.y * 64;
    if (EPI == 4) Bt += (size_t)(row0 >> 13) * Cn * Cn;   // per-batch B
    int lane = t & 63, w = t >> 6;
    int wr = w >> 1, wc = w & 1;
    int frow = lane & 15, fk = (lane >> 4) * 8;

    bf16x8 bfr[4][2][2];
#pragma unroll
    for (int kt = 0; kt < 4; ++kt)
#pragma unroll
        for (int ks = 0; ks < 2; ++ks)
#pragma unroll
            for (int n = 0; n < 2; ++n)
                bfr[kt][ks][n] = *(const bf16x8*)(
                    Bt + (long long)(col0 + wc * 32 + n * 16 + frow) * Cn
                       + kt * 64 + ks * 32 + fk);

    int srow_in_g = lane >> 3;
    int schunk = lane & 7;
    auto stageA = [&](int kt, int bf) {
#pragma unroll
        for (int i = 0; i < 4; ++i) {
            int g = w * 4 + i;
            int r = g * 8 + srow_in_g;
            int c = schunk ^ (r & 7);
            const unsigned short* src = A + (long long)(row0 + r) * Cn + kt * 64 + c * 8;
            GLOAD_LDS16(src, &As[bf][g * 8][0]);
        }
    };

    f32x4 acc[4][2];
#pragma unroll
    for (int m = 0; m < 4; ++m)
#pragma unroll
        for (int n = 0; n < 2; ++n) {
            acc[m][n][0] = 0.f; acc[m][n][1] = 0.f;
            acc[m][n][2] = 0.f; acc[m][n][3] = 0.f;
        }

    stageA(0, 0);
    int bf = 0;
#pragma unroll
    for (int kt = 0; kt < 4; ++kt) {
        if (kt < 3) {
            stageA(kt + 1, bf ^ 1);
            asm volatile("s_waitcnt vmcnt(4)" ::: "memory");
        } else {
            asm volatile("s_waitcnt vmcnt(0)" ::: "memory");
        }
        __builtin_amdgcn_s_barrier();
#pragma unroll
        for (int ks = 0; ks < 2; ++ks) {
#pragma unroll
            for (int m = 0; m < 4; ++m) {
                int arow = wr * 64 + m * 16 + frow;
                bf16x8 afr = *(const bf16x8*)&As[bf][arow][(ks * 32 + fk) ^ ((arow & 7) << 3)];
#pragma unroll
                for (int n = 0; n < 2; ++n)
                    acc[m][n] = __builtin_amdgcn_mfma_f32_16x16x32_bf16(afr, bfr[kt][ks][n],
                                                                        acc[m][n], 0, 0, 0);
            }
        }
        __builtin_amdgcn_s_barrier();
        bf ^= 1;
    }

    float spv[2];
    if (EPI == 3) {
#pragma unroll
        for (int n = 0; n < 2; ++n) {
            float m_ = mu[col0 + wc * 32 + n * 16 + frow];
            spv[n] = (m_ > 20.f) ? m_ : log1pf(expf(m_));
        }
    }
#pragma unroll
    for (int m = 0; m < 4; ++m) {
        int rbase = row0 + wr * 64 + m * 16 + (lane >> 4) * 4;
#pragma unroll
        for (int n = 0; n < 2; ++n) {
            int col = col0 + wc * 32 + n * 16 + frow;
            float bv = (EPI == 4) ? 0.0f : bias[col];
#pragma unroll
            for (int r = 0; r < 4; ++r) {
                long long idx = (long long)(rbase + r) * Cn + col;
                float v = acc[m][n][r] + bv;
                if (EPI == 0) {
                    outB[idx] = f2bf(v);
                } else if (EPI == 1) {
                    float sg = 1.0f / (1.0f + __expf(-1.702f * v));
                    outB[idx] = f2bf(v * sg);
                } else if (EPI == 2) {
                    outF[idx] = v + resid[idx];
                } else if (EPI == 3) {
                    float xv = v + resid[idx];
                    outF[idx] = xv;
                    outB2[idx] = f2bf(xv * spv[n]);
                } else {
                    outF[idx] = (v >= 0.0f) ? v : 0.01f * v;
                }
            }
        }
    }
}

// ---------------------------------------------------------------------------
// kv_gemm (MFMA) for BOTH streams: grid (32, 32, 2); z selects stream.
// ---------------------------------------------------------------------------
__global__ __launch_bounds__(256) void kv_gemm_kernel(
    const unsigned short* __restrict__ kbs0, const unsigned short* __restrict__ vbs0,
    float* __restrict__ kv0p,
    const unsigned short* __restrict__ kbs1, const unsigned short* __restrict__ vbs1,
    float* __restrict__ kv1p) {
    const unsigned short* kb = blockIdx.z ? kbs1 : kbs0;
    const unsigned short* vb = blockIdx.z ? vbs1 : vbs0;
    float* kv = blockIdx.z ? kv1p : kv0p;
    __shared__ unsigned short kl[256][36];
    __shared__ unsigned short vl[256][36];
    __shared__ float red[4][1024];
    int bh = blockIdx.x, b = bh >> 3, h = bh & 7;
    int n0 = blockIdx.y * 256;
    int t = threadIdx.x, lane = t & 63, w = t >> 6;
    {
        int r0 = t >> 2, ch = (t & 3) * 8;
        long long gbase = ((long long)(b * Nn + n0)) * Cn + h * Dn + ch;
#pragma unroll
        for (int i = 0; i < 4; ++i) {
            int r = r0 + i * 64;
            ushortx8 dk = *(const ushortx8*)(kb + gbase + (long long)r * Cn);
            ushortx8 dv = *(const ushortx8*)(vb + gbase + (long long)r * Cn);
            ushortx4 k0 = {dk[0], dk[1], dk[2], dk[3]};
            ushortx4 k1 = {dk[4], dk[5], dk[6], dk[7]};
            ushortx4 v0 = {dv[0], dv[1], dv[2], dv[3]};
            ushortx4 v1 = {dv[4], dv[5], dv[6], dv[7]};
            *(ushortx4*)&kl[r][ch]     = k0;
            *(ushortx4*)&kl[r][ch + 4] = k1;
            *(ushortx4*)&vl[r][ch]     = v0;
            *(ushortx4*)&vl[r][ch + 4] = v1;
        }
    }
    __syncthreads();
    int frow = lane & 15, fk = (lane >> 4) * 8;
    f32x4 acc[2][2];
#pragma unroll
    for (int m = 0; m < 2; ++m)
#pragma unroll
        for (int n = 0; n < 2; ++n) {
            acc[m][n][0] = 0.f; acc[m][n][1] = 0.f;
            acc[m][n][2] = 0.f; acc[m][n][3] = 0.f;
        }
    int nb = w * 64;
#pragma unroll
    for (int s = 0; s < 2; ++s) {
        int kk = nb + s * 32 + fk;
        bf16x8 a0, a1, b0, b1;
#pragma unroll
        for (int j = 0; j < 8; ++j) {
            a0[j] = (short)kl[kk + j][frow];
            a1[j] = (short)kl[kk + j][16 + frow];
            b0[j] = (short)vl[kk + j][frow];
            b1[j] = (short)vl[kk + j][16 + frow];
        }
        acc[0][0] = __builtin_amdgcn_mfma_f32_16x16x32_bf16(a0, b0, acc[0][0], 0, 0, 0);
        acc[0][1] = __builtin_amdgcn_mfma_f32_16x16x32_bf16(a0, b1, acc[0][1], 0, 0, 0);
        acc[1][0] = __builtin_amdgcn_mfma_f32_16x16x32_bf16(a1, b0, acc[1][0], 0, 0, 0);
        acc[1][1] = __builtin_amdgcn_mfma_f32_16x16x32_bf16(a1, b1, acc[1][1], 0, 0, 0);
    }
#pragma unroll
    for (int m = 0; m < 2; ++m)
#pragma unroll
        for (int n = 0; n < 2; ++n)
#pragma unroll
            for (int r = 0; r < 4; ++r)
                red[w][(m * 16 + (lane >> 4) * 4 + r) * 32 + n * 16 + frow] = acc[m][n][r];
    __syncthreads();
    float* out = kv + (long long)bh * 1024;
#pragma unroll
    for (int i = 0; i < 4; ++i) {
        int idx = t + i * 256;
        atomicAdd(out + idx, red[0][idx] + red[1][idx] + red[2][idx] + red[3][idx]);
    }
}

// ---------------------------------------------------------------------------
// attn epilogue (MFMA): out[128,32] = q + (q@KV0)*dinv0 + (q@KV1)*dinv1.
// ---------------------------------------------------------------------------
__global__ __launch_bounds__(256) void attn_out_kernel(
    const unsigned short* __restrict__ qb, const float* __restrict__ kv0,
    const float* __restrict__ ks0, const float* __restrict__ kv1,
    const float* __restrict__ ks1, unsigned short* __restrict__ outb) {
    __shared__ unsigned short BT[80][40];   // [col][k], padded stride 80B
    int bh = blockIdx.y;
    int b = bh >> 3, h = bh & 7;
    int n0 = blockIdx.x * 128;
    int t = threadIdx.x;
    {
        int e = t & 31, d0 = t >> 5;
        const float* KV0 = kv0 + (long long)bh * 1024;
        const float* KV1 = kv1 + (long long)bh * 1024;
#pragma unroll
        for (int i = 0; i < 4; ++i) {
            int d = d0 + 8 * i;
            BT[e][d]      = f2bf(KV0[d * 32 + e]);
            BT[32 + e][d] = f2bf(KV1[d * 32 + e]);
        }
        if (t < 32)            BT[64][t]      = f2bf(ks0[bh * 32 + t]);
        else if (t < 64)       BT[65][t - 32] = f2bf(ks1[bh * 32 + (t - 32)]);
        if (t < 224) {
            int c = 66 + (t >> 4), k2 = (t & 15) * 2;
            BT[c][k2] = 0; BT[c][k2 + 1] = 0;
        }
    }
    __syncthreads();

    int lane = t & 63, w = t >> 6;
    int frow = lane & 15, fk = (lane >> 4) * 8;
    bf16x8 bfr[5];
#pragma unroll
    for (int n = 0; n < 5; ++n)
        bfr[n] = *(const bf16x8*)&BT[n * 16 + frow][fk];

    f32x4 acc[2][5];
#pragma unroll
    for (int m = 0; m < 2; ++m)
#pragma unroll
        for (int n = 0; n < 5; ++n) {
            acc[m][n][0] = 0.f; acc[m][n][1] = 0.f;
            acc[m][n][2] = 0.f; acc[m][n][3] = 0.f;
        }
    long long grow0 = (long long)b * Nn + n0 + w * 32;
#pragma unroll
    for (int m = 0; m < 2; ++m) {
        bf16x8 afr = *(const bf16x8*)(qb + (grow0 + m * 16 + frow) * Cn + h * Dn + fk);
#pragma unroll
        for (int n = 0; n < 5; ++n)
            acc[m][n] = __builtin_amdgcn_mfma_f32_16x16x32_bf16(afr, bfr[n],
                                                                acc[m][n], 0, 0, 0);
    }
#pragma unroll
    for (int m = 0; m < 2; ++m) {
#pragma unroll
        for (int r = 0; r < 4; ++r) {
            float s0 = __shfl(acc[m][4][r], lane & 48, 64);
            float s1 = __shfl(acc[m][4][r], (lane & 48) + 1, 64);
            float inv0 = 1.0f / s0, inv1 = 1.0f / s1;
            long long row = grow0 + m * 16 + (lane >> 4) * 4 + r;
            long long base = row * Cn + h * Dn + (lane & 15);
            float q0 = bf2f(qb[base]), q1 = bf2f(qb[base + 16]);
            outb[base]      = f2bf(q0 + acc[m][0][r] * inv0 + acc[m][2][r] * inv1);
            outb[base + 16] = f2bf(q1 + acc[m][1][r] * inv0 + acc[m][3][r] * inv1);
        }
    }
}

// ---------------------------------------------------------------------------
// Batched transpose + bf16 cast:  out[b][c][n] = bf16(in[b][n][c]).
// ---------------------------------------------------------------------------
__global__ __launch_bounds__(256) void transpose_cast_kernel(
    const float* __restrict__ in, unsigned short* __restrict__ out) {
    __shared__ float tile[64][33];
    int b = blockIdx.z;
    int n0 = blockIdx.x * 64;
    int c0 = blockIdx.y * 32;
    int t = threadIdx.x;
    int r = t >> 2;
    int cc = (t & 3) * 8;
    const float* src = in + ((long long)b * Nn + n0 + r) * Cn + c0 + cc;
    float4 a0 = *(const float4*)src;
    float4 a1 = *(const float4*)(src + 4);
    tile[r][cc + 0] = a0.x; tile[r][cc + 1] = a0.y;
    tile[r][cc + 2] = a0.z; tile[r][cc + 3] = a0.w;
    tile[r][cc + 4] = a1.x; tile[r][cc + 5] = a1.y;
    tile[r][cc + 6] = a1.z; tile[r][cc + 7] = a1.w;
    __syncthreads();
    int c = t >> 3;
    int nn = (t & 7) * 8;
    ushortx8 o;
#pragma unroll
    for (int j = 0; j < 8; ++j) o[j] = f2bf(tile[nn + j][c]);
    *(ushortx8*)(out + ((long long)b * Cn + c0 + c) * Nn + n0 + nn) = o;
}

// ---------------------------------------------------------------------------
// Split-K bilinear GEMM: xtfxT[b][f][c] += sum_{k-range} fxT[b][f][k]*xT[b][c][k]
// 16 splits of K=512.  grid (2, 4, 64).
// ---------------------------------------------------------------------------
__global__ __launch_bounds__(256, 2) void bilin_gemm_kernel(
    const unsigned short* __restrict__ A, const unsigned short* __restrict__ Bm,
    float* __restrict__ Cacc) {
    __shared__ unsigned short As[128][72];
    __shared__ unsigned short Bs[64][72];
    int t = threadIdx.x;
    int b = blockIdx.z >> 4;
    int split = blockIdx.z & 15;
    int row0 = blockIdx.x * 128;   // f
    int col0 = blockIdx.y * 64;    // c
    const unsigned short* Ab = A + (long long)b * Cn * Nn;
    const unsigned short* Bb = Bm + (long long)b * Cn * Nn;
    int lane = t & 63, w = t >> 6;
    int wr = w >> 1, wc = w & 1;
    int frow = lane & 15, fk = (lane >> 4) * 8;
    f32x4 acc[4][2];
#pragma unroll
    for (int m = 0; m < 4; ++m)
#pragma unroll
        for (int n = 0; n < 2; ++n) {
            acc[m][n][0] = 0.f; acc[m][n][1] = 0.f;
            acc[m][n][2] = 0.f; acc[m][n][3] = 0.f;
        }
    int sr = t >> 3, sc = (t & 7) * 8;
    for (int kt = 0; kt < 8; ++kt) {
        int k0 = split * 512 + kt * 64;
#pragma unroll
        for (int p = 0; p < 4; ++p) {
            int rr = sr + p * 32;
            ushortx8 d = *(const ushortx8*)(Ab + (long long)(row0 + rr) * Nn + k0 + sc);
            *(ushortx8*)&As[rr][sc] = d;
        }
#pragma unroll
        for (int p = 0; p < 2; ++p) {
            int br = sr + p * 32;
            ushortx8 d = *(const ushortx8*)(Bb + (long long)(col0 + br) * Nn + k0 + sc);
            *(ushortx8*)&Bs[br][sc] = d;
        }
        __syncthreads();
#pragma unroll
        for (int ks = 0; ks < 2; ++ks) {
            bf16x8 bfr[2];
#pragma unroll
            for (int n = 0; n < 2; ++n)
                bfr[n] = *(const bf16x8*)&Bs[wc * 32 + n * 16 + frow][ks * 32 + fk];
#pragma unroll
            for (int m = 0; m < 4; ++m) {
                bf16x8 afr = *(const bf16x8*)&As[wr * 64 + m * 16 + frow][ks * 32 + fk];
#pragma unroll
                for (int n = 0; n < 2; ++n)
                    acc[m][n] = __builtin_amdgcn_mfma_f32_16x16x32_bf16(afr, bfr[n],
                                                                        acc[m][n], 0, 0, 0);
            }
        }
        __syncthreads();
    }
    float* base = Cacc + (long long)b * Cn * Cn;
#pragma unroll
    for (int m = 0; m < 4; ++m) {
        int rbase = row0 + wr * 64 + m * 16 + (lane >> 4) * 4;
#pragma unroll
        for (int n = 0; n < 2; ++n) {
            int col = col0 + wc * 32 + n * 16 + frow;
#pragma unroll
            for (int r = 0; r < 4; ++r)
                atomicAdd(base + (long long)(rbase + r) * Cn + col, acc[m][n][r]);
        }
    }
}

// fp32 -> bf16 cast, 4 elems/thread.
__global__ __launch_bounds__(256) void castf2b_kernel(const float* __restrict__ in,
                                                      unsigned short* __restrict__ out) {
    int i = (blockIdx.x * 256 + threadIdx.x) * 4;
    float4 v = *(const float4*)(in + i);
    ushortx4 o;
    o.x = f2bf(v.x); o.y = f2bf(v.y); o.z = f2bf(v.z); o.w = f2bf(v.w);
    *(ushortx4*)(out + i) = o;
}

// ---------------------------------------------------------------------------
extern "C" void kernel_launch(void* const* d_in, const int* in_sizes, int n_in,
                              void* d_out, int out_size, void* d_ws, size_t ws_size,
                              hipStream_t stream) {
    const float* input  = (const float*)d_in[0];
    const float* fx     = (const float*)d_in[1];
    const float* inputf = (const float*)d_in[2];
    const float* ln1g = (const float*)d_in[3],  *ln1b = (const float*)d_in[4];
    const float* ln2g = (const float*)d_in[5],  *ln2b = (const float*)d_in[6];
    const float* ln3g = (const float*)d_in[7],  *ln3b = (const float*)d_in[8];
    const float* Wq  = (const float*)d_in[9],   *bq  = (const float*)d_in[10];
    const float* Wk0 = (const float*)d_in[11],  *bk0 = (const float*)d_in[12];
    const float* Wv0 = (const float*)d_in[13],  *bv0 = (const float*)d_in[14];
    const float* Wk1 = (const float*)d_in[15],  *bk1 = (const float*)d_in[16];
    const float* Wv1 = (const float*)d_in[17],  *bv1 = (const float*)d_in[18];
    const float* Wo  = (const float*)d_in[19],  *bo  = (const float*)d_in[20];
    const float* Wm1 = (const float*)d_in[21],  *bm1 = (const float*)d_in[22];
    const float* Wm2 = (const float*)d_in[23],  *bm2 = (const float*)d_in[24];
    const float* mu  = (const float*)d_in[25];

    float* xOut  = (float*)d_out;        // output 0: x
    float* fxOut = xOut + S;             // output 1: fx_new

    char* ws = (char*)d_ws;
    const size_t SB = (size_t)S * 2;     // 16 MB bf16 buffer
    unsigned short* x1b  = (unsigned short*)(ws + 0 * SB);
    unsigned short* f1b  = (unsigned short*)(ws + 1 * SB);
    unsigned short* qb   = (unsigned short*)(ws + 2 * SB);
    unsigned short* kb   = (unsigned short*)(ws + 3 * SB);
    unsigned short* vb   = (unsigned short*)(ws + 4 * SB);
    unsigned short* outb = (unsigned short*)(ws + 5 * SB);
    unsigned short* kb2  = (unsigned short*)(ws + 6 * SB);
    unsigned short* vb2  = (unsigned short*)(ws + 7 * SB);
    unsigned short* Wt   = (unsigned short*)(ws + 8 * SB);               // 8 x 64K bf16
    unsigned short* xtT  = (unsigned short*)(ws + 8 * SB + (size_t)8 * 65536 * 2);
    float* zbase = (float*)(ws + 8 * SB + (size_t)8 * 65536 * 2 + (size_t)Bn * 65536 * 2);
    float* kv0   = zbase;                 // 32768
    float* kv1   = zbase + 32768;         // 32768
    float* ks0   = zbase + 65536;         // 1024
    float* ks1   = zbase + 66560;         // 1024
    float* xtfxT = zbase + 67584;         // 262144  [b][f][c]
    const size_t ZFLOATS = 67584 + 262144;

    hipMemsetAsync(zbase, 0, ZFLOATS * sizeof(float), stream);

    wtrans_all_kernel<<<dim3(8, 8), 256, 0, stream>>>(Wq, Wk0, Wv0, Wk1, Wv1, Wo, Wm1, Wm2, Wt);

    peln2_kernel<<<dim3(BN / 4, 2), 256, 0, stream>>>(input, ln1g, ln1b, x1b,
                                                      inputf, ln2g, ln2b, f1b);

    // ALL 5 QKV GEMMs in one dispatch (both streams), 128x128 tiles
    qkv_gemm_kernel<<<dim3(BN / 128, 10), 256, 0, stream>>>(
        f1b, x1b, Wt, bq, bk0, bv0, bk1, bv1,
        qb, kb, vb, kb2, vb2, ks0, ks1);
    // both kv reductions in one dispatch
    kv_gemm_kernel<<<dim3(32, 32, 2), 256, 0, stream>>>(kb, vb, kv0, kb2, vb2, kv1);

    attn_out_kernel<<<dim3(Nn / 128, Bn * Hn), 256, 0, stream>>>(qb, kv0, ks0, kv1, ks1, outb);

    dim3 ggrid(BN / 128, 4);
    // x = out @ Wo + bo + input   -> d_out[0] (fp32)
    gemm_kernel<2><<<ggrid, 256, 0, stream>>>(outb, Wt + (size_t)5 * 65536, bo,
                                              xOut, input, nullptr, nullptr, nullptr);
    // MLP
    ln_kernel<<<BN / 4, 256, 0, stream>>>(xOut, ln3g, ln3b, f1b);
    gemm_kernel<1><<<ggrid, 256, 0, stream>>>(f1b, Wt + (size_t)6 * 65536, bm1,
                                              nullptr, nullptr, x1b, nullptr, nullptr);
    gemm_kernel<3><<<ggrid, 256, 0, stream>>>(x1b, Wt + (size_t)7 * 65536, bm2,
                                              xOut, xOut, nullptr, qb, mu);

    // bilinear fx update
    transpose_cast_kernel<<<dim3(Nn / 64, Cn / 32, Bn), 256, 0, stream>>>(xOut, kb);  // xT
    transpose_cast_kernel<<<dim3(Nn / 64, Cn / 32, Bn), 256, 0, stream>>>(fx,   vb);  // fxT
    bilin_gemm_kernel<<<dim3(2, 4, 64), 256, 0, stream>>>(vb, kb, xtfxT);
    castf2b_kernel<<<(int)(Bn * 65536 / 1024), 256, 0, stream>>>(xtfxT, xtT);
    gemm_kernel<4><<<ggrid, 256, 0, stream>>>(qb, xtT, nullptr,
                                              fxOut, nullptr, nullptr, nullptr, nullptr);
}